// Round 3
// baseline (2976.416 us; speedup 1.0000x reference)
//
#include <hip/hip_runtime.h>
#include <math.h>

// ---- static problem config (matches reference) ----
namespace {
constexpr int N  = 102400;   // nodes
constexpr int E  = 819200;   // edges
constexpr int B_ = 16;       // graphs
constexpr int G  = 72;       // voxel cells per graph (8 x 9)
constexpr int GX = 8;
constexpr int NB = N / 256;  // 400 blocks over nodes
constexpr int EB = E / 256;  // 3200 blocks over edges
constexpr int CGRID = 2048;  // conv grid: 8 blocks/CU = exact residency at 4 waves/EU
constexpr int TOTW  = CGRID * 2;  // total waves per conv dispatch
}

// ================= CSR build =================

__global__ __launch_bounds__(256) void count_kernel(const int* __restrict__ ei,
                                                    int* __restrict__ cnt) {
  int e = blockIdx.x * 256 + threadIdx.x;
  atomicAdd(&cnt[ei[E + e]], 1);
}

__global__ __launch_bounds__(256) void rcnt_kernel(const int* __restrict__ cnt,
                                                   float* __restrict__ rcnt) {
  int n = blockIdx.x * 256 + threadIdx.x;
  rcnt[n] = 1.0f / (float)max(cnt[n], 1);
}

// per-256-chunk sums of cnt
__global__ __launch_bounds__(256) void reduce_cnt(const int* __restrict__ cnt,
                                                  int* __restrict__ bsum) {
  __shared__ int s[256];
  int i = blockIdx.x * 256 + threadIdx.x;
  s[threadIdx.x] = cnt[i];
  __syncthreads();
  for (int st = 128; st > 0; st >>= 1) {
    if (threadIdx.x < st) s[threadIdx.x] += s[threadIdx.x + st];
    __syncthreads();
  }
  if (threadIdx.x == 0) bsum[blockIdx.x] = s[0];
}

// single-block exclusive scan of the NB block sums
__global__ __launch_bounds__(512) void scan_bsum(const int* __restrict__ bsum,
                                                 int* __restrict__ boff) {
  __shared__ int s[512];
  int i = threadIdx.x;
  int v = (i < NB) ? bsum[i] : 0;
  s[i] = v;
  __syncthreads();
  for (int st = 1; st < 512; st <<= 1) {
    int t = (i >= st) ? s[i - st] : 0;
    __syncthreads();
    s[i] += t;
    __syncthreads();
  }
  if (i < NB) boff[i] = s[i] - v;  // exclusive
}

// rowptr[n] = exclusive scan of cnt; cursor = rowptr; sdesc[n] = (beg, end)
__global__ __launch_bounds__(256) void write_rowptr(const int* __restrict__ cnt,
                                                    const int* __restrict__ boff,
                                                    int* __restrict__ rowptr,
                                                    int* __restrict__ cursor,
                                                    int2* __restrict__ sdesc) {
  __shared__ int s[256];
  int i = blockIdx.x * 256 + threadIdx.x;
  int v = cnt[i];
  s[threadIdx.x] = v;
  __syncthreads();
  for (int st = 1; st < 256; st <<= 1) {
    int t = (threadIdx.x >= st) ? s[threadIdx.x - st] : 0;
    __syncthreads();
    s[threadIdx.x] += t;
    __syncthreads();
  }
  int off = boff[blockIdx.x] + s[threadIdx.x] - v;  // exclusive
  rowptr[i] = off;
  cursor[i] = off;
  sdesc[i] = make_int2(off, off + v);
  if (i == N - 1) rowptr[N] = off + v;
}

// scatter edge records (src + clamped pseudo-coords) into CSR order
__global__ __launch_bounds__(256) void edge_scatter(const int* __restrict__ ei,
                                                    const float* __restrict__ ea,
                                                    int* __restrict__ cursor,
                                                    float4* __restrict__ rec) {
  int e = blockIdx.x * 256 + threadIdx.x;
  int src = ei[e];
  int dst = ei[E + e];
  float u0 = fminf(fmaxf(ea[3 * e + 0], 0.f), 1.f);
  float u1 = fminf(fmaxf(ea[3 * e + 1], 0.f), 1.f);
  float u2 = fminf(fmaxf(ea[3 * e + 2], 0.f), 1.f);
  int slot = atomicAdd(&cursor[dst], 1);
  rec[slot] = make_float4(__int_as_float(src), u0, u1, u2);
}

// ================= pooling helper =================
__device__ __forceinline__ void atomicMaxFloat(float* addr, float val) {
  if (val >= 0.f)
    atomicMax(reinterpret_cast<int*>(addr), __float_as_int(val));
  else
    atomicMin(reinterpret_cast<unsigned int*>(addr), __float_as_uint(val));
}

// ====== v9: register-only factored spline conv — no LDS, no barrier ======
// out[n] = (1/deg) * sum_k ( sum_{e->n} b_k(e) * x_src(e) ) @ W[k]
//
// Round-14 (post-mortem of v8): v8 proved (a) the register-only epilogue is
// numerically correct (absmax 0.0) and (b) occupancy rises to 58% without
// LDS. But __launch_bounds__(128,6) capped VGPRs at ~85 while the body needs
// ~100-130 (agg[32] + o[COUT] + 3-deep pipeline) -> allocator spilled the
// arrays to scratch: 1.6 GB/dispatch HBM traffic at 2.2 TB/s == the whole
// 739 us. Fix #1: __launch_bounds__(128, 4) -> cap 128, no spill.
// Fix #2: residency-round quantization (R0/R1 lesson: grid 1.25x resident
// -> 2 lockstep rounds -> 37% occupancy). At 4 waves/EU the resident set is
// exactly 8 two-wave blocks/CU = 2048 blocks. So launch EXACTLY 2048 blocks
// for every conv; each wave owns a contiguous run of NPW*REPS nodes with
// REPS = ceil(N / (4096*NPW)); all node indices clamp to N-1 (tail waves
// recompute node N-1 with identical inputs -> identical value -> benign).
// Single exact round, no ceil() loss, tail quantum = one 2-wave block.
template <int CIN, int COUT, bool RES, bool POOL>
__global__ __launch_bounds__(128, 4) void node_conv_v9(
    const float* __restrict__ X, const float* __restrict__ W,
    const float4* __restrict__ rec, const int2* __restrict__ sdesc,
    const float* __restrict__ rcnt, const float* __restrict__ res,
    float* __restrict__ Y, const float* __restrict__ pos,
    const int* __restrict__ batch, float* __restrict__ pooled) {
  const int tid  = threadIdx.x;
  const int wave = tid >> 6;
  const int lane = tid & 63;

  // XCD swizzle: consecutive sb (hence node ranges) land on one XCD
  const int sb = (blockIdx.x & 7) * (CGRID >> 3) + (blockIdx.x >> 3);
  const int wid = sb * 2 + wave;

  const float4* W4 = reinterpret_cast<const float4*>(W);

  if constexpr (CIN >= 8) {
    constexpr int QN   = CIN / 4;          // channel quads per row
    constexpr int LPN  = 8 * QN;           // lanes per node
    constexpr int NPW  = 64 / LPN;         // nodes per wave per rep
    constexpr int REPS = (N + TOTW * NPW - 1) / (TOTW * NPW);

    const int nbase = wid * (NPW * REPS);

    const int ci4  = lane % QN;
    const int esub = (lane / QN) & 7;
    const int ns   = lane / LPN;
    const int kstar = ((lane / QN) & 1) * 4 + ((lane / (2 * QN)) & 1) * 2 +
                      ((lane / (4 * QN)) & 1);
    const int l = lane & (LPN - 1);        // lane-in-node

    auto nodeAt = [&](int rep) -> int {
      return min(nbase + ns + rep * NPW, N - 1);
    };
    auto loadDesc = [&](int rep) -> int2 { return sdesc[nodeAt(rep)]; };
    auto loadRec = [&](int e) -> float4 { return rec[min(e, E - 1)]; };
    auto loadX = [&](const float4& r) -> float4 {
      int src = __float_as_int(r.x);
      return *(reinterpret_cast<const float4*>(X + (size_t)src * CIN) + ci4);
    };

    // channel owned after the output reduce: bit-reversal of l (log2(COUT) bits)
    int ch = 0;
#pragma unroll
    for (int s = 0; (1 << s) < COUT; s++)
      if (l & (1 << s)) ch += COUT >> (s + 1);

    // pipeline prologue
    int2 d0 = loadDesc(0);
    int2 d1 = loadDesc(1);
    int2 d2 = loadDesc(2);
    float4 ra0 = loadRec(d0.x + esub), rb0 = loadRec(d0.x + esub + 8);
    float4 ra1 = loadRec(d1.x + esub), rb1 = loadRec(d1.x + esub + 8);
    float4 xa0 = loadX(ra0), xb0 = loadX(rb0);

#pragma unroll 1
    for (int rep = 0; rep < REPS; rep++) {
      // issue next-rep x pair (recs arrived one rep ago)
      float4 xa1 = loadX(ra1), xb1 = loadX(rb1);
      // issue rep+2 rec pair (desc arrived one rep ago)
      float4 ra2 = loadRec(d2.x + esub), rb2 = loadRec(d2.x + esub + 8);
      // issue rep+3 desc
      int2 d3 = loadDesc(rep + 3);

      const int n = nodeAt(rep);
      const float rc = rcnt[n];

      float agg[32];
#pragma unroll
      for (int i = 0; i < 32; i++) agg[i] = 0.f;

      auto accum = [&](const float4& r, const float4& v, bool valid) {
        float uy = r.y, uz = r.z, uw = r.w;
        float py = 1.f - uy, pz = 1.f - uz, pw = 1.f - uw;
        float g = valid ? 1.f : 0.f;
        float t0 = py * pz * g, t1 = uy * pz * g;
        float t2 = py * uz * g, t3 = uy * uz * g;
        float b[8] = {t0 * pw, t1 * pw, t2 * pw, t3 * pw,
                      t0 * uw, t1 * uw, t2 * uw, t3 * uw};
#pragma unroll
        for (int k = 0; k < 8; k++) {
          agg[k * 4 + 0] = fmaf(b[k], v.x, agg[k * 4 + 0]);
          agg[k * 4 + 1] = fmaf(b[k], v.y, agg[k * 4 + 1]);
          agg[k * 4 + 2] = fmaf(b[k], v.z, agg[k * 4 + 2]);
          agg[k * 4 + 3] = fmaf(b[k], v.w, agg[k * 4 + 3]);
        }
      };

      accum(ra0, xa0, d0.x + esub < d0.y);
      accum(rb0, xb0, d0.x + esub + 8 < d0.y);
      // rare: deg > 16 (P ~ 0.4%), exposed-latency fallback
#pragma unroll 1
      for (int e = d0.x + esub + 16; e < d0.y; e += 8) {
        float4 rr = rec[e];
        float4 xx = loadX(rr);
        accum(rr, xx, true);
      }

      // phase-1 reduce-and-split over esub bits; payload 32 -> 16 -> 8 -> 4
#pragma unroll
      for (int s = 0; s < 3; s++) {
        const int m = QN << s;
        const int H = 16 >> s;
        bool up = (lane & m) != 0;
#pragma unroll
        for (int i = 0; i < H; i++) {
          float keep = up ? agg[i + H] : agg[i];
          float send = up ? agg[i] : agg[i + H];
          agg[i] = keep + __shfl_xor(send, m, 64);
        }
      }
      // lane now holds quad A[kstar][ci4*4 .. ci4*4+3] in agg[0..3]

      // ---- in-register W product: o[co] += agg[j] * W[kstar][ci4*4+j][co]
      int wb = (kstar * CIN + ci4 * 4) * (COUT / 4);
      asm volatile("" : "+v"(wb));  // defeat LICM: keep W streaming from L1
      float o[COUT];
#pragma unroll
      for (int i = 0; i < COUT; i++) o[i] = 0.f;
#pragma unroll
      for (int j = 0; j < 4; j++) {
        float aj = agg[j];
#pragma unroll
        for (int c = 0; c < COUT / 4; c++) {
          float4 w = W4[wb + j * (COUT / 4) + c];
          o[4 * c + 0] = fmaf(aj, w.x, o[4 * c + 0]);
          o[4 * c + 1] = fmaf(aj, w.y, o[4 * c + 1]);
          o[4 * c + 2] = fmaf(aj, w.z, o[4 * c + 2]);
          o[4 * c + 3] = fmaf(aj, w.w, o[4 * c + 3]);
        }
      }

      // ---- output reduce-split across the node's LPN lanes ----
#pragma unroll
      for (int s = 0; (1 << s) < COUT; s++) {
        const int m = 1 << s;
        const int H = COUT >> (s + 1);
        bool up = (l & m) != 0;
#pragma unroll
        for (int i = 0; i < H; i++) {
          float keep = up ? o[i + H] : o[i];
          float send = up ? o[i] : o[i + H];
          o[i] = keep + __shfl_xor(send, m, 64);
        }
      }
#pragma unroll
      for (int m = COUT; m < LPN; m <<= 1) o[0] += __shfl_xor(o[0], m, 64);

      // ---- epilogue: rcnt / ELU / residual / store (one scalar per lane)
      if (l < COUT) {
        float v = o[0] * rc;
        v = v > 0.f ? v : expm1f(v);
        if constexpr (RES) v += res[(size_t)n * COUT + ch];
        if constexpr (POOL) {
          int cx = (int)floorf(pos[n * 3 + 0] / 16.0f);
          int cy = (int)floorf(pos[n * 3 + 1] / 12.0f);
          int cl = batch[n] * G + cy * GX + cx;
          atomicMaxFloat(&pooled[cl * 32 + ch], v);
        } else {
          Y[(size_t)n * COUT + ch] = v;
        }
      }

      // rotate pipeline
      d0 = d1; d1 = d2; d2 = d3;
      ra0 = ra1; rb0 = rb1; ra1 = ra2; rb1 = rb2;
      xa0 = xa1; xb0 = xb1;
    }
  } else {
    // CIN == 1: lane = (node_sub, k); serial edge walk with prefetch
    constexpr int LPN  = 8;
    constexpr int NPW  = 8;
    constexpr int REPS = (N + TOTW * NPW - 1) / (TOTW * NPW);
    const int nbase = wid * (NPW * REPS);
    const int ns = lane / LPN;
    const int k  = lane & 7;
    const int l  = lane & 7;

    auto nodeAt = [&](int rep) -> int {
      return min(nbase + ns + rep * NPW, N - 1);
    };

    // channel owned after the output reduce: bitrev3(l)
    int ch = ((l & 1) << 2) | (l & 2) | ((l >> 2) & 1);

    int2 seC = sdesc[nodeAt(0)];
    int2 seN = sdesc[nodeAt(1)];
    float4 rcC = make_float4(0.f, 0.f, 0.f, 0.f);
    bool vC = seC.x < seC.y;
    if (vC) rcC = rec[seC.x];

#pragma unroll 1
    for (int rep = 0; rep < REPS; rep++) {
      bool vN = (rep + 1 < REPS) && (seN.x < seN.y);
      float4 rcN = make_float4(0.f, 0.f, 0.f, 0.f);
      if (vN) rcN = rec[seN.x];
      int2 seNN = (rep + 2 < REPS) ? sdesc[nodeAt(rep + 2)] : seN;

      const int n = nodeAt(rep);
      const float rc = rcnt[n];

      float a0 = 0.f;
      if (vC) {
        float4 r = rcC;
        int e = seC.x + 1;
        while (true) {
          bool more = e < seC.y;
          float4 rn = r;
          if (more) rn = rec[e];
          int src = __float_as_int(r.x);
          float f0 = (k & 1) ? r.y : 1.f - r.y;
          float f1 = (k & 2) ? r.z : 1.f - r.z;
          float f2 = (k & 4) ? r.w : 1.f - r.w;
          a0 = fmaf(f0 * f1 * f2, X[src], a0);
          if (!more) break;
          r = rn;
          e++;
        }
      }

      // o[co] = a0 * W[k][0][co]  (COUT == 8)
      float o[8];
      {
        float4 w0 = W4[k * 2 + 0];
        float4 w1 = W4[k * 2 + 1];
        o[0] = a0 * w0.x; o[1] = a0 * w0.y; o[2] = a0 * w0.z; o[3] = a0 * w0.w;
        o[4] = a0 * w1.x; o[5] = a0 * w1.y; o[6] = a0 * w1.z; o[7] = a0 * w1.w;
      }
      // reduce-split over the node's 8 lanes: payload 8 -> 4 -> 2 -> 1
#pragma unroll
      for (int s = 0; s < 3; s++) {
        const int m = 1 << s;
        const int H = 8 >> (s + 1);
        bool up = (l & m) != 0;
#pragma unroll
        for (int i = 0; i < H; i++) {
          float keep = up ? o[i + H] : o[i];
          float send = up ? o[i] : o[i + H];
          o[i] = keep + __shfl_xor(send, m, 64);
        }
      }

      float v = o[0] * rc;
      v = v > 0.f ? v : expm1f(v);
      Y[(size_t)n * 8 + ch] = v;

      seC = seN;
      seN = seNN;
      vC = vN;
      rcC = rcN;
    }
  }
}

// ================= final FC =================
__global__ __launch_bounds__(256) void fc_kernel(const float* __restrict__ pooled,
                                                 const float* __restrict__ fcw,
                                                 float* __restrict__ out) {
  int b = blockIdx.x >> 1;
  int o = blockIdx.x & 1;
  const float* pb = pooled + b * (G * 32);
  float s = 0.f;
  for (int i = threadIdx.x; i < G * 32; i += 256) {
    float v = pb[i];
    v = isfinite(v) ? v : 0.f;  // untouched cells (0xFF memset -> NaN) -> 0
    s += v * fcw[i * 2 + o];
  }
  __shared__ float red[256];
  red[threadIdx.x] = s;
  __syncthreads();
  for (int st = 128; st > 0; st >>= 1) {
    if (threadIdx.x < st) red[threadIdx.x] += red[threadIdx.x + st];
    __syncthreads();
  }
  if (threadIdx.x == 0) out[b * 2 + o] = red[0];
}

extern "C" void kernel_launch(void* const* d_in, const int* in_sizes, int n_in,
                              void* d_out, int out_size, void* d_ws, size_t ws_size,
                              hipStream_t stream) {
  const float* x     = (const float*)d_in[0];
  const float* pos   = (const float*)d_in[1];
  const float* ea    = (const float*)d_in[2];
  const int*   ei    = (const int*)d_in[3];
  const int*   batch = (const int*)d_in[4];
  const float* fcw   = (const float*)d_in[5];
  const float* w1    = (const float*)d_in[6];
  const float* w2    = (const float*)d_in[7];
  const float* w3    = (const float*)d_in[8];
  const float* w4    = (const float*)d_in[9];
  const float* w5    = (const float*)d_in[10];
  const float* w6    = (const float*)d_in[11];
  const float* w7    = (const float*)d_in[12];
  float* out = (float*)d_out;

  // ---- workspace layout (256B-aligned chunks) ----
  char* ws = (char*)d_ws;
  size_t off = 0;
  auto alloc = [&](size_t bytes) {
    size_t p = off;
    off += (bytes + 255) & ~(size_t)255;
    return ws + p;
  };
  float*  rcnt   = (float*)alloc((size_t)N * 4);
  int*    cnt    = (int*)alloc((size_t)N * 4);
  int*    rowptr = (int*)alloc((size_t)(N + 1) * 4);
  int*    cursor = (int*)alloc((size_t)N * 4);
  int*    bsum   = (int*)alloc(512 * 4);
  int*    boff   = (int*)alloc(512 * 4);
  int2*   sdesc  = (int2*)alloc((size_t)N * 8);
  float4* rec    = (float4*)alloc((size_t)E * 16);
  float*  bufA   = (float*)alloc((size_t)N * 32 * 4);
  float*  bufB   = (float*)alloc((size_t)N * 32 * 4);
  float*  bufC   = (float*)alloc((size_t)N * 32 * 4);
  float*  pooled = (float*)alloc((size_t)B_ * G * 32 * 4);

  // ---- CSR build ----
  hipMemsetAsync(cnt, 0, (size_t)N * 4, stream);
  count_kernel<<<EB, 256, 0, stream>>>(ei, cnt);
  rcnt_kernel<<<NB, 256, 0, stream>>>(cnt, rcnt);
  reduce_cnt<<<NB, 256, 0, stream>>>(cnt, bsum);
  scan_bsum<<<1, 512, 0, stream>>>(bsum, boff);
  write_rowptr<<<NB, 256, 0, stream>>>(cnt, boff, rowptr, cursor, sdesc);
  edge_scatter<<<EB, 256, 0, stream>>>(ei, ea, cursor, rec);

  // ---- pooled init (must precede conv7) ----
  hipMemsetAsync(pooled, 0xFF, (size_t)B_ * G * 32 * 4, stream);

  // ---- conv ladder: fixed 2048-block grid, register-only, no LDS ----
  // conv1: 1->8    x -> A     REPS=4
  node_conv_v9<1, 8, false, false><<<CGRID, 128, 0, stream>>>(
      x, w1, rec, sdesc, rcnt, nullptr, bufA, nullptr, nullptr, nullptr);
  // conv2: 8->16   A -> B     REPS=7
  node_conv_v9<8, 16, false, false><<<CGRID, 128, 0, stream>>>(
      bufA, w2, rec, sdesc, rcnt, nullptr, bufB, nullptr, nullptr, nullptr);
  // conv3: 16->16  B -> C     REPS=13
  node_conv_v9<16, 16, false, false><<<CGRID, 128, 0, stream>>>(
      bufB, w3, rec, sdesc, rcnt, nullptr, bufC, nullptr, nullptr, nullptr);
  // conv4: 16->16  C -> A, + residual B
  node_conv_v9<16, 16, true, false><<<CGRID, 128, 0, stream>>>(
      bufC, w4, rec, sdesc, rcnt, bufB, bufA, nullptr, nullptr, nullptr);
  // conv5: 16->32  A -> C     REPS=13
  node_conv_v9<16, 32, false, false><<<CGRID, 128, 0, stream>>>(
      bufA, w5, rec, sdesc, rcnt, nullptr, bufC, nullptr, nullptr, nullptr);
  // conv6: 32->32  C -> B     REPS=25
  node_conv_v9<32, 32, false, false><<<CGRID, 128, 0, stream>>>(
      bufC, w6, rec, sdesc, rcnt, nullptr, bufB, nullptr, nullptr, nullptr);
  // conv7: 32->32  B -> (pool), + residual C
  node_conv_v9<32, 32, true, true><<<CGRID, 128, 0, stream>>>(
      bufB, w7, rec, sdesc, rcnt, bufC, nullptr, pos, batch, pooled);

  // ---- FC ----
  fc_kernel<<<B_ * 2, 256, 0, stream>>>(pooled, fcw, out);
}

// Round 5
// 1700.546 us; speedup vs baseline: 1.7503x; 1.7503x over previous
//
#include <hip/hip_runtime.h>
#include <math.h>

// ---- static problem config (matches reference) ----
namespace {
constexpr int N  = 102400;   // nodes
constexpr int E  = 819200;   // edges
constexpr int B_ = 16;       // graphs
constexpr int G  = 72;       // voxel cells per graph (8 x 9)
constexpr int GX = 8;
constexpr int NB = N / 256;  // 400 blocks over nodes
constexpr int EB = E / 256;  // 3200 blocks over edges
constexpr int CGRID = 3200;  // conv grid: 32 nodes/block, all blocks resident
}

// ================= CSR build =================

__global__ __launch_bounds__(256) void count_kernel(const int* __restrict__ ei,
                                                    int* __restrict__ cnt) {
  int e = blockIdx.x * 256 + threadIdx.x;
  atomicAdd(&cnt[ei[E + e]], 1);
}

__global__ __launch_bounds__(256) void rcnt_kernel(const int* __restrict__ cnt,
                                                   float* __restrict__ rcnt) {
  int n = blockIdx.x * 256 + threadIdx.x;
  rcnt[n] = 1.0f / (float)max(cnt[n], 1);
}

// per-256-chunk sums of cnt
__global__ __launch_bounds__(256) void reduce_cnt(const int* __restrict__ cnt,
                                                  int* __restrict__ bsum) {
  __shared__ int s[256];
  int i = blockIdx.x * 256 + threadIdx.x;
  s[threadIdx.x] = cnt[i];
  __syncthreads();
  for (int st = 128; st > 0; st >>= 1) {
    if (threadIdx.x < st) s[threadIdx.x] += s[threadIdx.x + st];
    __syncthreads();
  }
  if (threadIdx.x == 0) bsum[blockIdx.x] = s[0];
}

// single-block exclusive scan of the NB block sums
__global__ __launch_bounds__(512) void scan_bsum(const int* __restrict__ bsum,
                                                 int* __restrict__ boff) {
  __shared__ int s[512];
  int i = threadIdx.x;
  int v = (i < NB) ? bsum[i] : 0;
  s[i] = v;
  __syncthreads();
  for (int st = 1; st < 512; st <<= 1) {
    int t = (i >= st) ? s[i - st] : 0;
    __syncthreads();
    s[i] += t;
    __syncthreads();
  }
  if (i < NB) boff[i] = s[i] - v;  // exclusive
}

// rowptr[n] = exclusive scan of cnt; cursor = rowptr; sdesc[n] = (beg, end)
__global__ __launch_bounds__(256) void write_rowptr(const int* __restrict__ cnt,
                                                    const int* __restrict__ boff,
                                                    int* __restrict__ rowptr,
                                                    int* __restrict__ cursor,
                                                    int2* __restrict__ sdesc) {
  __shared__ int s[256];
  int i = blockIdx.x * 256 + threadIdx.x;
  int v = cnt[i];
  s[threadIdx.x] = v;
  __syncthreads();
  for (int st = 1; st < 256; st <<= 1) {
    int t = (threadIdx.x >= st) ? s[threadIdx.x - st] : 0;
    __syncthreads();
    s[threadIdx.x] += t;
    __syncthreads();
  }
  int off = boff[blockIdx.x] + s[threadIdx.x] - v;  // exclusive
  rowptr[i] = off;
  cursor[i] = off;
  sdesc[i] = make_int2(off, off + v);
  if (i == N - 1) rowptr[N] = off + v;
}

// scatter edge records (src + clamped pseudo-coords) into CSR order
__global__ __launch_bounds__(256) void edge_scatter(const int* __restrict__ ei,
                                                    const float* __restrict__ ea,
                                                    int* __restrict__ cursor,
                                                    float4* __restrict__ rec) {
  int e = blockIdx.x * 256 + threadIdx.x;
  int src = ei[e];
  int dst = ei[E + e];
  float u0 = fminf(fmaxf(ea[3 * e + 0], 0.f), 1.f);
  float u1 = fminf(fmaxf(ea[3 * e + 1], 0.f), 1.f);
  float u2 = fminf(fmaxf(ea[3 * e + 2], 0.f), 1.f);
  int slot = atomicAdd(&cursor[dst], 1);
  rec[slot] = make_float4(__int_as_float(src), u0, u1, u2);
}

// ================= pooling helper =================
__device__ __forceinline__ void atomicMaxFloat(float* addr, float val) {
  if (val >= 0.f)
    atomicMax(reinterpret_cast<int*>(addr), __float_as_int(val));
  else
    atomicMin(reinterpret_cast<unsigned int*>(addr), __float_as_uint(val));
}

// ====== v10b: LDS-bridged conv, persistent 3200-block grid, 8KB LDS ======
// out[n] = (1/deg) * sum_k ( sum_{e->n} b_k(e) * x_src(e) ) @ W[k]
//
// Round-16: v10 failed correctness (absmax 6.7e-4) because the CIN==1
// branch dropped the `wave` term from its LDS slot arithmetic when REPS was
// re-derived for 2 waves: both waves computed nodes 0..15 of each chunk and
// nodes 16..31 read never-written LDS. The CIN>=8 branch kept the term
// (slot0 = wave*(REPS*NPW)+ns) and is correct. This version restores the
// wave term in the CIN==1 branch; everything else is byte-identical to v10.
// Structure (R4 theory, still to be validated by counters):
//  (1) phase-2 float2/thread (TPN=COUT/2) -> NPB halved -> 8 KB LDS/block
//      -> resident cap 16 blocks/CU (wave-limited, VGPR<=64 via bounds(128,8)).
//  (2) every conv: 32 nodes/block (K chunks x NPB), grid = 3200 exactly;
//      all blocks resident from t=0, zero tail, zero round-quantization.
//      Sustained occupancy = 12.5 blocks/CU = 25 waves/CU = 78%.
template <int CIN, int COUT, bool RES, bool POOL, int K>
__global__ __launch_bounds__(128, 8) void node_conv_v10(
    const float* __restrict__ X, const float* __restrict__ W,
    const float4* __restrict__ rec, const int2* __restrict__ sdesc,
    const float* __restrict__ rcnt, const float* __restrict__ res,
    float* __restrict__ Y, const float* __restrict__ pos,
    const int* __restrict__ batch, float* __restrict__ pooled) {
  constexpr int TPN  = COUT / 2;                    // phase-2 threads per node
  constexpr int NPB  = 128 / TPN;                   // nodes per block-chunk
  constexpr int ROWF = (CIN >= 8) ? 8 * CIN : 12;   // LDS floats per node row

  __shared__ float sAgg[NPB * ROWF];

  const int tid  = threadIdx.x;
  const int wave = tid >> 6;
  const int lane = tid & 63;

  // XCD swizzle: consecutive 32-node block ranges land on one XCD
  const int sb = (blockIdx.x & 7) * (CGRID >> 3) + (blockIdx.x >> 3);
  const int bbase = sb * (K * NPB);

  const int node_l = tid / TPN;
  const int co2    = tid % TPN;

  const float2* W2 = reinterpret_cast<const float2*>(W);

#pragma unroll 1
  for (int g = 0; g < K; g++) {
    const int nbase = bbase + g * NPB;

    // ---- phase-2 epilogue gathers hoisted to chunk top (overlap phase 1) ----
    const int n2 = nbase + node_l;
    const float rc = rcnt[n2];
    float2 rres = make_float2(0.f, 0.f);
    if constexpr (RES)
      rres = *reinterpret_cast<const float2*>(res + (size_t)n2 * COUT + co2 * 2);
    float p0 = 0.f, p1 = 0.f;
    int bi = 0;
    if constexpr (POOL) {
      p0 = pos[n2 * 3 + 0];
      p1 = pos[n2 * 3 + 1];
      bi = batch[n2];
    }

    // ---------------- phase 1 ----------------
    if constexpr (CIN >= 8) {
      constexpr int QN   = CIN / 4;          // channel quads per row
      constexpr int LPN  = 8 * QN;           // lanes per node
      constexpr int NPW  = 64 / LPN;         // nodes per wave per rep
      constexpr int REPS = NPB / (2 * NPW);  // reps per wave

      const int ci4  = lane % QN;
      const int esub = (lane / QN) & 7;
      const int ns   = lane / LPN;
      const int kstar = ((lane / QN) & 1) * 4 + ((lane / (2 * QN)) & 1) * 2 +
                        ((lane / (4 * QN)) & 1);
      const int slot0 = wave * (REPS * NPW) + ns;  // local slot of rep 0

      auto loadDesc = [&](int rep) -> int2 {
        int r = min(rep, REPS - 1);
        return sdesc[nbase + slot0 + r * NPW];
      };
      auto loadRec = [&](int e) -> float4 { return rec[min(e, E - 1)]; };
      auto loadX = [&](const float4& r) -> float4 {
        int src = __float_as_int(r.x);
        return *(reinterpret_cast<const float4*>(X + (size_t)src * CIN) + ci4);
      };

      // pipeline prologue
      int2 d0 = loadDesc(0);
      int2 d1 = loadDesc(1);
      int2 d2 = loadDesc(2);
      float4 ra0 = loadRec(d0.x + esub), rb0 = loadRec(d0.x + esub + 8);
      float4 ra1 = loadRec(d1.x + esub), rb1 = loadRec(d1.x + esub + 8);
      float4 xa0 = loadX(ra0), xb0 = loadX(rb0);

#pragma unroll 1
      for (int rep = 0; rep < REPS; rep++) {
        // issue next-rep x pair (recs arrived one rep ago)
        float4 xa1 = loadX(ra1), xb1 = loadX(rb1);
        // issue rep+2 rec pair (desc arrived one rep ago)
        float4 ra2 = loadRec(d2.x + esub), rb2 = loadRec(d2.x + esub + 8);
        // issue rep+3 desc
        int2 d3 = loadDesc(rep + 3);

        float agg[32];
#pragma unroll
        for (int i = 0; i < 32; i++) agg[i] = 0.f;

        auto accum = [&](const float4& r, const float4& v, bool valid) {
          float uy = r.y, uz = r.z, uw = r.w;
          float py = 1.f - uy, pz = 1.f - uz, pw = 1.f - uw;
          float g2 = valid ? 1.f : 0.f;
          float t0 = py * pz * g2, t1 = uy * pz * g2;
          float t2 = py * uz * g2, t3 = uy * uz * g2;
          float b[8] = {t0 * pw, t1 * pw, t2 * pw, t3 * pw,
                        t0 * uw, t1 * uw, t2 * uw, t3 * uw};
#pragma unroll
          for (int k = 0; k < 8; k++) {
            agg[k * 4 + 0] = fmaf(b[k], v.x, agg[k * 4 + 0]);
            agg[k * 4 + 1] = fmaf(b[k], v.y, agg[k * 4 + 1]);
            agg[k * 4 + 2] = fmaf(b[k], v.z, agg[k * 4 + 2]);
            agg[k * 4 + 3] = fmaf(b[k], v.w, agg[k * 4 + 3]);
          }
        };

        accum(ra0, xa0, d0.x + esub < d0.y);
        accum(rb0, xb0, d0.x + esub + 8 < d0.y);
        // rare: deg > 16 (P ~ 0.4%), exposed-latency fallback
#pragma unroll 1
        for (int e = d0.x + esub + 16; e < d0.y; e += 8) {
          float4 rr = rec[e];
          float4 xx = loadX(rr);
          accum(rr, xx, true);
        }

        // reduce-and-split over esub bits; payload 32 -> 16 -> 8 -> 4
#pragma unroll
        for (int s = 0; s < 3; s++) {
          const int m = QN << s;
          const int H = 16 >> s;
          bool up = (lane & m) != 0;
#pragma unroll
          for (int i = 0; i < H; i++) {
            float keep = up ? agg[i + H] : agg[i];
            float send = up ? agg[i] : agg[i + H];
            agg[i] = keep + __shfl_xor(send, m, 64);
          }
        }

        const int sl = slot0 + rep * NPW;
        const int idx4 = (kstar * QN + ci4) ^ (sl & 7);  // block swizzle
        *reinterpret_cast<float4*>(&sAgg[sl * ROWF + idx4 * 4]) =
            make_float4(agg[0], agg[1], agg[2], agg[3]);

        // rotate pipeline
        d0 = d1; d1 = d2; d2 = d3;
        ra0 = ra1; rb0 = rb1; ra1 = ra2; rb1 = rb2;
        xa0 = xa1; xb0 = xb1;
      }
    } else {
      // CIN == 1: lane = (node_sub, k); serial edge walk with prefetch
      constexpr int LPN  = 8;
      constexpr int NPW  = 8;
      constexpr int REPS = NPB / (2 * NPW);
      const int ns = lane / LPN;
      const int k  = lane & 7;
      // v10b FIX: restore the wave term (v10 dropped it -> nodes 16..31 of
      // each chunk read never-written LDS; both waves computed nodes 0..15)
      const int slotbase = nbase + wave * (REPS * NPW) + ns;

      int2 seC = sdesc[slotbase];
      int2 seN = (REPS > 1) ? sdesc[slotbase + NPW] : seC;
      float4 rcC = make_float4(0.f, 0.f, 0.f, 0.f);
      bool vC = seC.x < seC.y;
      if (vC) rcC = rec[seC.x];

#pragma unroll 1
      for (int rep = 0; rep < REPS; rep++) {
        bool vN = (rep + 1 < REPS) && (seN.x < seN.y);
        float4 rcN = make_float4(0.f, 0.f, 0.f, 0.f);
        if (vN) rcN = rec[seN.x];
        int2 seNN = (rep + 2 < REPS) ? sdesc[slotbase + (rep + 2) * NPW] : seN;

        float a0 = 0.f;
        if (vC) {
          float4 r = rcC;
          int e = seC.x + 1;
          while (true) {
            bool more = e < seC.y;
            float4 rn = r;
            if (more) rn = rec[e];
            int src = __float_as_int(r.x);
            float f0 = (k & 1) ? r.y : 1.f - r.y;
            float f1 = (k & 2) ? r.z : 1.f - r.z;
            float f2 = (k & 4) ? r.w : 1.f - r.w;
            a0 = fmaf(f0 * f1 * f2, X[src], a0);
            if (!more) break;
            r = rn;
            e++;
          }
        }

        // v10b FIX: wave term restored here as well
        const int sl = wave * (REPS * NPW) + rep * NPW + ns;
        sAgg[sl * ROWF + k] = a0;

        seC = seN;
        seN = seNN;
        vC = vN;
        rcC = rcN;
      }
    }
    __syncthreads();

    // ---------------- phase 2 (float2 per thread) ----------------
    float2 acc = make_float2(0.f, 0.f);
    const float* arow = &sAgg[node_l * ROWF];

    if constexpr (CIN == 1) {
#pragma unroll
      for (int kk = 0; kk < 8; kk++) {
        float a = arow[kk];
        float2 w = W2[kk * TPN + co2];
        acc.x = fmaf(a, w.x, acc.x);
        acc.y = fmaf(a, w.y, acc.y);
      }
    } else {
      constexpr int Q = CIN / 4;
      const int swz = node_l & 7;
#pragma unroll 2
      for (int kk = 0; kk < 8; kk++) {
#pragma unroll
        for (int c = 0; c < Q; c++) {
          float4 a4 = *reinterpret_cast<const float4*>(
              &arow[((kk * Q + c) ^ swz) * 4]);
          float2 w0 = W2[(kk * CIN + 4 * c + 0) * TPN + co2];
          float2 w1 = W2[(kk * CIN + 4 * c + 1) * TPN + co2];
          float2 w2 = W2[(kk * CIN + 4 * c + 2) * TPN + co2];
          float2 w3 = W2[(kk * CIN + 4 * c + 3) * TPN + co2];
          acc.x = fmaf(a4.x, w0.x, acc.x);
          acc.y = fmaf(a4.x, w0.y, acc.y);
          acc.x = fmaf(a4.y, w1.x, acc.x);
          acc.y = fmaf(a4.y, w1.y, acc.y);
          acc.x = fmaf(a4.z, w2.x, acc.x);
          acc.y = fmaf(a4.z, w2.y, acc.y);
          acc.x = fmaf(a4.w, w3.x, acc.x);
          acc.y = fmaf(a4.w, w3.y, acc.y);
        }
      }
    }

    float v0 = acc.x * rc;
    float v1 = acc.y * rc;
    v0 = v0 > 0.f ? v0 : expm1f(v0);
    v1 = v1 > 0.f ? v1 : expm1f(v1);
    if constexpr (RES) {
      v0 += rres.x;
      v1 += rres.y;
    }

    if constexpr (POOL) {
      int cx = (int)floorf(p0 / 16.0f);
      int cy = (int)floorf(p1 / 12.0f);
      int cl = bi * G + cy * GX + cx;
      atomicMaxFloat(&pooled[cl * 32 + co2 * 2 + 0], v0);
      atomicMaxFloat(&pooled[cl * 32 + co2 * 2 + 1], v1);
    } else {
      *reinterpret_cast<float2*>(Y + (size_t)n2 * COUT + co2 * 2) =
          make_float2(v0, v1);
    }
    __syncthreads();  // protect sAgg before next chunk's phase 1
  }
}

// ================= final FC =================
__global__ __launch_bounds__(256) void fc_kernel(const float* __restrict__ pooled,
                                                 const float* __restrict__ fcw,
                                                 float* __restrict__ out) {
  int b = blockIdx.x >> 1;
  int o = blockIdx.x & 1;
  const float* pb = pooled + b * (G * 32);
  float s = 0.f;
  for (int i = threadIdx.x; i < G * 32; i += 256) {
    float v = pb[i];
    v = isfinite(v) ? v : 0.f;  // untouched cells (0xFF memset -> NaN) -> 0
    s += v * fcw[i * 2 + o];
  }
  __shared__ float red[256];
  red[threadIdx.x] = s;
  __syncthreads();
  for (int st = 128; st > 0; st >>= 1) {
    if (threadIdx.x < st) red[threadIdx.x] += red[threadIdx.x + st];
    __syncthreads();
  }
  if (threadIdx.x == 0) out[b * 2 + o] = red[0];
}

extern "C" void kernel_launch(void* const* d_in, const int* in_sizes, int n_in,
                              void* d_out, int out_size, void* d_ws, size_t ws_size,
                              hipStream_t stream) {
  const float* x     = (const float*)d_in[0];
  const float* pos   = (const float*)d_in[1];
  const float* ea    = (const float*)d_in[2];
  const int*   ei    = (const int*)d_in[3];
  const int*   batch = (const int*)d_in[4];
  const float* fcw   = (const float*)d_in[5];
  const float* w1    = (const float*)d_in[6];
  const float* w2    = (const float*)d_in[7];
  const float* w3    = (const float*)d_in[8];
  const float* w4    = (const float*)d_in[9];
  const float* w5    = (const float*)d_in[10];
  const float* w6    = (const float*)d_in[11];
  const float* w7    = (const float*)d_in[12];
  float* out = (float*)d_out;

  // ---- workspace layout (256B-aligned chunks) ----
  char* ws = (char*)d_ws;
  size_t off = 0;
  auto alloc = [&](size_t bytes) {
    size_t p = off;
    off += (bytes + 255) & ~(size_t)255;
    return ws + p;
  };
  float*  rcnt   = (float*)alloc((size_t)N * 4);
  int*    cnt    = (int*)alloc((size_t)N * 4);
  int*    rowptr = (int*)alloc((size_t)(N + 1) * 4);
  int*    cursor = (int*)alloc((size_t)N * 4);
  int*    bsum   = (int*)alloc(512 * 4);
  int*    boff   = (int*)alloc(512 * 4);
  int2*   sdesc  = (int2*)alloc((size_t)N * 8);
  float4* rec    = (float4*)alloc((size_t)E * 16);
  float*  bufA   = (float*)alloc((size_t)N * 32 * 4);
  float*  bufB   = (float*)alloc((size_t)N * 32 * 4);
  float*  bufC   = (float*)alloc((size_t)N * 32 * 4);
  float*  pooled = (float*)alloc((size_t)B_ * G * 32 * 4);

  // ---- CSR build ----
  hipMemsetAsync(cnt, 0, (size_t)N * 4, stream);
  count_kernel<<<EB, 256, 0, stream>>>(ei, cnt);
  rcnt_kernel<<<NB, 256, 0, stream>>>(cnt, rcnt);
  reduce_cnt<<<NB, 256, 0, stream>>>(cnt, bsum);
  scan_bsum<<<1, 512, 0, stream>>>(bsum, boff);
  write_rowptr<<<NB, 256, 0, stream>>>(cnt, boff, rowptr, cursor, sdesc);
  edge_scatter<<<EB, 256, 0, stream>>>(ei, ea, cursor, rec);

  // ---- pooled init (must precede conv7) ----
  hipMemsetAsync(pooled, 0xFF, (size_t)B_ * G * 32 * 4, stream);

  // ---- conv ladder: persistent 3200-block grid, 32 nodes/block, 8KB LDS ----
  // conv1: 1->8    x -> A     NPB=32 K=1
  node_conv_v10<1, 8, false, false, 1><<<CGRID, 128, 0, stream>>>(
      x, w1, rec, sdesc, rcnt, nullptr, bufA, nullptr, nullptr, nullptr);
  // conv2: 8->16   A -> B     NPB=16 K=2
  node_conv_v10<8, 16, false, false, 2><<<CGRID, 128, 0, stream>>>(
      bufA, w2, rec, sdesc, rcnt, nullptr, bufB, nullptr, nullptr, nullptr);
  // conv3: 16->16  B -> C     NPB=16 K=2
  node_conv_v10<16, 16, false, false, 2><<<CGRID, 128, 0, stream>>>(
      bufB, w3, rec, sdesc, rcnt, nullptr, bufC, nullptr, nullptr, nullptr);
  // conv4: 16->16  C -> A, + residual B
  node_conv_v10<16, 16, true, false, 2><<<CGRID, 128, 0, stream>>>(
      bufC, w4, rec, sdesc, rcnt, bufB, bufA, nullptr, nullptr, nullptr);
  // conv5: 16->32  A -> C     NPB=8 K=4
  node_conv_v10<16, 32, false, false, 4><<<CGRID, 128, 0, stream>>>(
      bufA, w5, rec, sdesc, rcnt, nullptr, bufC, nullptr, nullptr, nullptr);
  // conv6: 32->32  C -> B     NPB=8 K=4
  node_conv_v10<32, 32, false, false, 4><<<CGRID, 128, 0, stream>>>(
      bufC, w6, rec, sdesc, rcnt, nullptr, bufB, nullptr, nullptr, nullptr);
  // conv7: 32->32  B -> (pool), + residual C
  node_conv_v10<32, 32, true, true, 4><<<CGRID, 128, 0, stream>>>(
      bufB, w7, rec, sdesc, rcnt, bufC, nullptr, pos, batch, pooled);

  // ---- FC ----
  fc_kernel<<<B_ * 2, 256, 0, stream>>>(pooled, fcw, out);
}

// Round 6
// 1174.766 us; speedup vs baseline: 2.5336x; 1.4476x over previous
//
#include <hip/hip_runtime.h>
#include <math.h>

// ---- static problem config (matches reference) ----
namespace {
constexpr int N  = 102400;   // nodes
constexpr int E  = 819200;   // edges
constexpr int B_ = 16;       // graphs
constexpr int G  = 72;       // voxel cells per graph (8 x 9)
constexpr int GX = 8;
constexpr int NB = N / 256;  // 400 blocks over nodes
constexpr int EB = E / 256;  // 3200 blocks over edges
constexpr int CGRID = 3200;  // conv grid: 32 nodes/block, all blocks resident
}

// ================= CSR build =================

__global__ __launch_bounds__(256) void count_kernel(const int* __restrict__ ei,
                                                    int* __restrict__ cnt) {
  int e = blockIdx.x * 256 + threadIdx.x;
  atomicAdd(&cnt[ei[E + e]], 1);
}

__global__ __launch_bounds__(256) void rcnt_kernel(const int* __restrict__ cnt,
                                                   float* __restrict__ rcnt) {
  int n = blockIdx.x * 256 + threadIdx.x;
  rcnt[n] = 1.0f / (float)max(cnt[n], 1);
}

// per-256-chunk sums of cnt
__global__ __launch_bounds__(256) void reduce_cnt(const int* __restrict__ cnt,
                                                  int* __restrict__ bsum) {
  __shared__ int s[256];
  int i = blockIdx.x * 256 + threadIdx.x;
  s[threadIdx.x] = cnt[i];
  __syncthreads();
  for (int st = 128; st > 0; st >>= 1) {
    if (threadIdx.x < st) s[threadIdx.x] += s[threadIdx.x + st];
    __syncthreads();
  }
  if (threadIdx.x == 0) bsum[blockIdx.x] = s[0];
}

// single-block exclusive scan of the NB block sums
__global__ __launch_bounds__(512) void scan_bsum(const int* __restrict__ bsum,
                                                 int* __restrict__ boff) {
  __shared__ int s[512];
  int i = threadIdx.x;
  int v = (i < NB) ? bsum[i] : 0;
  s[i] = v;
  __syncthreads();
  for (int st = 1; st < 512; st <<= 1) {
    int t = (i >= st) ? s[i - st] : 0;
    __syncthreads();
    s[i] += t;
    __syncthreads();
  }
  if (i < NB) boff[i] = s[i] - v;  // exclusive
}

// rowptr[n] = exclusive scan of cnt; cursor = rowptr; sdesc[n] = (beg, end)
__global__ __launch_bounds__(256) void write_rowptr(const int* __restrict__ cnt,
                                                    const int* __restrict__ boff,
                                                    int* __restrict__ rowptr,
                                                    int* __restrict__ cursor,
                                                    int2* __restrict__ sdesc) {
  __shared__ int s[256];
  int i = blockIdx.x * 256 + threadIdx.x;
  int v = cnt[i];
  s[threadIdx.x] = v;
  __syncthreads();
  for (int st = 1; st < 256; st <<= 1) {
    int t = (threadIdx.x >= st) ? s[threadIdx.x - st] : 0;
    __syncthreads();
    s[threadIdx.x] += t;
    __syncthreads();
  }
  int off = boff[blockIdx.x] + s[threadIdx.x] - v;  // exclusive
  rowptr[i] = off;
  cursor[i] = off;
  sdesc[i] = make_int2(off, off + v);
  if (i == N - 1) rowptr[N] = off + v;
}

// scatter edge records (src + clamped pseudo-coords) into CSR order
__global__ __launch_bounds__(256) void edge_scatter(const int* __restrict__ ei,
                                                    const float* __restrict__ ea,
                                                    int* __restrict__ cursor,
                                                    float4* __restrict__ rec) {
  int e = blockIdx.x * 256 + threadIdx.x;
  int src = ei[e];
  int dst = ei[E + e];
  float u0 = fminf(fmaxf(ea[3 * e + 0], 0.f), 1.f);
  float u1 = fminf(fmaxf(ea[3 * e + 1], 0.f), 1.f);
  float u2 = fminf(fmaxf(ea[3 * e + 2], 0.f), 1.f);
  int slot = atomicAdd(&cursor[dst], 1);
  rec[slot] = make_float4(__int_as_float(src), u0, u1, u2);
}

// ================= pooling helper =================
__device__ __forceinline__ void atomicMaxFloat(float* addr, float val) {
  if (val >= 0.f)
    atomicMax(reinterpret_cast<int*>(addr), __float_as_int(val));
  else
    atomicMin(reinterpret_cast<unsigned int*>(addr), __float_as_uint(val));
}

// ====== v11: LDS-bridged conv, persistent 3200-block grid, 8KB LDS ======
// out[n] = (1/deg) * sum_k ( sum_{e->n} b_k(e) * x_src(e) ) @ W[k]
//
// Round-17. v10b (bounds(128,8)) passed but spilled: the 8-waves/EU hint
// capped VGPR at 64 and the backend down-allocated to 32(!), scratch-
// round-tripping agg[32] -> 1.05 GB/dispatch, 471 us = pure spill BW.
// Allocator rule established over v7/v8/v10b: body's natural footprint is
// ~56 VGPR; any declared cap <= 64 triggers down-allocation + spill;
// bounds(128,6) (85-reg budget) yields 56 VGPR, zero spill (v7 measured).
// ONLY change vs v10b: __launch_bounds__(128, 6). Actual occupancy is set
// by the ACHIEVED VGPR count (56 <= 64 -> 8 waves/SIMD still reachable);
// LDS 8KB/block never binds (16 blocks/CU = 128KB); grid 3200 = 12.5
// blocks/CU stays fully resident -> sustained ~25 waves/CU.
template <int CIN, int COUT, bool RES, bool POOL, int K>
__global__ __launch_bounds__(128, 6) void node_conv_v11(
    const float* __restrict__ X, const float* __restrict__ W,
    const float4* __restrict__ rec, const int2* __restrict__ sdesc,
    const float* __restrict__ rcnt, const float* __restrict__ res,
    float* __restrict__ Y, const float* __restrict__ pos,
    const int* __restrict__ batch, float* __restrict__ pooled) {
  constexpr int TPN  = COUT / 2;                    // phase-2 threads per node
  constexpr int NPB  = 128 / TPN;                   // nodes per block-chunk
  constexpr int ROWF = (CIN >= 8) ? 8 * CIN : 12;   // LDS floats per node row

  __shared__ float sAgg[NPB * ROWF];

  const int tid  = threadIdx.x;
  const int wave = tid >> 6;
  const int lane = tid & 63;

  // XCD swizzle: consecutive 32-node block ranges land on one XCD
  const int sb = (blockIdx.x & 7) * (CGRID >> 3) + (blockIdx.x >> 3);
  const int bbase = sb * (K * NPB);

  const int node_l = tid / TPN;
  const int co2    = tid % TPN;

  const float2* W2 = reinterpret_cast<const float2*>(W);

#pragma unroll 1
  for (int g = 0; g < K; g++) {
    const int nbase = bbase + g * NPB;

    // ---- phase-2 epilogue gathers hoisted to chunk top (overlap phase 1) ----
    const int n2 = nbase + node_l;
    const float rc = rcnt[n2];
    float2 rres = make_float2(0.f, 0.f);
    if constexpr (RES)
      rres = *reinterpret_cast<const float2*>(res + (size_t)n2 * COUT + co2 * 2);
    float p0 = 0.f, p1 = 0.f;
    int bi = 0;
    if constexpr (POOL) {
      p0 = pos[n2 * 3 + 0];
      p1 = pos[n2 * 3 + 1];
      bi = batch[n2];
    }

    // ---------------- phase 1 ----------------
    if constexpr (CIN >= 8) {
      constexpr int QN   = CIN / 4;          // channel quads per row
      constexpr int LPN  = 8 * QN;           // lanes per node
      constexpr int NPW  = 64 / LPN;         // nodes per wave per rep
      constexpr int REPS = NPB / (2 * NPW);  // reps per wave

      const int ci4  = lane % QN;
      const int esub = (lane / QN) & 7;
      const int ns   = lane / LPN;
      const int kstar = ((lane / QN) & 1) * 4 + ((lane / (2 * QN)) & 1) * 2 +
                        ((lane / (4 * QN)) & 1);
      const int slot0 = wave * (REPS * NPW) + ns;  // local slot of rep 0

      auto loadDesc = [&](int rep) -> int2 {
        int r = min(rep, REPS - 1);
        return sdesc[nbase + slot0 + r * NPW];
      };
      auto loadRec = [&](int e) -> float4 { return rec[min(e, E - 1)]; };
      auto loadX = [&](const float4& r) -> float4 {
        int src = __float_as_int(r.x);
        return *(reinterpret_cast<const float4*>(X + (size_t)src * CIN) + ci4);
      };

      // pipeline prologue
      int2 d0 = loadDesc(0);
      int2 d1 = loadDesc(1);
      int2 d2 = loadDesc(2);
      float4 ra0 = loadRec(d0.x + esub), rb0 = loadRec(d0.x + esub + 8);
      float4 ra1 = loadRec(d1.x + esub), rb1 = loadRec(d1.x + esub + 8);
      float4 xa0 = loadX(ra0), xb0 = loadX(rb0);

#pragma unroll 1
      for (int rep = 0; rep < REPS; rep++) {
        // issue next-rep x pair (recs arrived one rep ago)
        float4 xa1 = loadX(ra1), xb1 = loadX(rb1);
        // issue rep+2 rec pair (desc arrived one rep ago)
        float4 ra2 = loadRec(d2.x + esub), rb2 = loadRec(d2.x + esub + 8);
        // issue rep+3 desc
        int2 d3 = loadDesc(rep + 3);

        float agg[32];
#pragma unroll
        for (int i = 0; i < 32; i++) agg[i] = 0.f;

        auto accum = [&](const float4& r, const float4& v, bool valid) {
          float uy = r.y, uz = r.z, uw = r.w;
          float py = 1.f - uy, pz = 1.f - uz, pw = 1.f - uw;
          float g2 = valid ? 1.f : 0.f;
          float t0 = py * pz * g2, t1 = uy * pz * g2;
          float t2 = py * uz * g2, t3 = uy * uz * g2;
          float b[8] = {t0 * pw, t1 * pw, t2 * pw, t3 * pw,
                        t0 * uw, t1 * uw, t2 * uw, t3 * uw};
#pragma unroll
          for (int k = 0; k < 8; k++) {
            agg[k * 4 + 0] = fmaf(b[k], v.x, agg[k * 4 + 0]);
            agg[k * 4 + 1] = fmaf(b[k], v.y, agg[k * 4 + 1]);
            agg[k * 4 + 2] = fmaf(b[k], v.z, agg[k * 4 + 2]);
            agg[k * 4 + 3] = fmaf(b[k], v.w, agg[k * 4 + 3]);
          }
        };

        accum(ra0, xa0, d0.x + esub < d0.y);
        accum(rb0, xb0, d0.x + esub + 8 < d0.y);
        // rare: deg > 16 (P ~ 0.4%), exposed-latency fallback
#pragma unroll 1
        for (int e = d0.x + esub + 16; e < d0.y; e += 8) {
          float4 rr = rec[e];
          float4 xx = loadX(rr);
          accum(rr, xx, true);
        }

        // reduce-and-split over esub bits; payload 32 -> 16 -> 8 -> 4
#pragma unroll
        for (int s = 0; s < 3; s++) {
          const int m = QN << s;
          const int H = 16 >> s;
          bool up = (lane & m) != 0;
#pragma unroll
          for (int i = 0; i < H; i++) {
            float keep = up ? agg[i + H] : agg[i];
            float send = up ? agg[i] : agg[i + H];
            agg[i] = keep + __shfl_xor(send, m, 64);
          }
        }

        const int sl = slot0 + rep * NPW;
        const int idx4 = (kstar * QN + ci4) ^ (sl & 7);  // block swizzle
        *reinterpret_cast<float4*>(&sAgg[sl * ROWF + idx4 * 4]) =
            make_float4(agg[0], agg[1], agg[2], agg[3]);

        // rotate pipeline
        d0 = d1; d1 = d2; d2 = d3;
        ra0 = ra1; rb0 = rb1; ra1 = ra2; rb1 = rb2;
        xa0 = xa1; xb0 = xb1;
      }
    } else {
      // CIN == 1: lane = (node_sub, k); serial edge walk with prefetch
      constexpr int LPN  = 8;
      constexpr int NPW  = 8;
      constexpr int REPS = NPB / (2 * NPW);
      const int ns = lane / LPN;
      const int k  = lane & 7;
      const int slotbase = nbase + wave * (REPS * NPW) + ns;

      int2 seC = sdesc[slotbase];
      int2 seN = (REPS > 1) ? sdesc[slotbase + NPW] : seC;
      float4 rcC = make_float4(0.f, 0.f, 0.f, 0.f);
      bool vC = seC.x < seC.y;
      if (vC) rcC = rec[seC.x];

#pragma unroll 1
      for (int rep = 0; rep < REPS; rep++) {
        bool vN = (rep + 1 < REPS) && (seN.x < seN.y);
        float4 rcN = make_float4(0.f, 0.f, 0.f, 0.f);
        if (vN) rcN = rec[seN.x];
        int2 seNN = (rep + 2 < REPS) ? sdesc[slotbase + (rep + 2) * NPW] : seN;

        float a0 = 0.f;
        if (vC) {
          float4 r = rcC;
          int e = seC.x + 1;
          while (true) {
            bool more = e < seC.y;
            float4 rn = r;
            if (more) rn = rec[e];
            int src = __float_as_int(r.x);
            float f0 = (k & 1) ? r.y : 1.f - r.y;
            float f1 = (k & 2) ? r.z : 1.f - r.z;
            float f2 = (k & 4) ? r.w : 1.f - r.w;
            a0 = fmaf(f0 * f1 * f2, X[src], a0);
            if (!more) break;
            r = rn;
            e++;
          }
        }

        const int sl = wave * (REPS * NPW) + rep * NPW + ns;
        sAgg[sl * ROWF + k] = a0;

        seC = seN;
        seN = seNN;
        vC = vN;
        rcC = rcN;
      }
    }
    __syncthreads();

    // ---------------- phase 2 (float2 per thread) ----------------
    float2 acc = make_float2(0.f, 0.f);
    const float* arow = &sAgg[node_l * ROWF];

    if constexpr (CIN == 1) {
#pragma unroll
      for (int kk = 0; kk < 8; kk++) {
        float a = arow[kk];
        float2 w = W2[kk * TPN + co2];
        acc.x = fmaf(a, w.x, acc.x);
        acc.y = fmaf(a, w.y, acc.y);
      }
    } else {
      constexpr int Q = CIN / 4;
      const int swz = node_l & 7;
#pragma unroll 2
      for (int kk = 0; kk < 8; kk++) {
#pragma unroll
        for (int c = 0; c < Q; c++) {
          float4 a4 = *reinterpret_cast<const float4*>(
              &arow[((kk * Q + c) ^ swz) * 4]);
          float2 w0 = W2[(kk * CIN + 4 * c + 0) * TPN + co2];
          float2 w1 = W2[(kk * CIN + 4 * c + 1) * TPN + co2];
          float2 w2 = W2[(kk * CIN + 4 * c + 2) * TPN + co2];
          float2 w3 = W2[(kk * CIN + 4 * c + 3) * TPN + co2];
          acc.x = fmaf(a4.x, w0.x, acc.x);
          acc.y = fmaf(a4.x, w0.y, acc.y);
          acc.x = fmaf(a4.y, w1.x, acc.x);
          acc.y = fmaf(a4.y, w1.y, acc.y);
          acc.x = fmaf(a4.z, w2.x, acc.x);
          acc.y = fmaf(a4.z, w2.y, acc.y);
          acc.x = fmaf(a4.w, w3.x, acc.x);
          acc.y = fmaf(a4.w, w3.y, acc.y);
        }
      }
    }

    float v0 = acc.x * rc;
    float v1 = acc.y * rc;
    v0 = v0 > 0.f ? v0 : expm1f(v0);
    v1 = v1 > 0.f ? v1 : expm1f(v1);
    if constexpr (RES) {
      v0 += rres.x;
      v1 += rres.y;
    }

    if constexpr (POOL) {
      int cx = (int)floorf(p0 / 16.0f);
      int cy = (int)floorf(p1 / 12.0f);
      int cl = bi * G + cy * GX + cx;
      atomicMaxFloat(&pooled[cl * 32 + co2 * 2 + 0], v0);
      atomicMaxFloat(&pooled[cl * 32 + co2 * 2 + 1], v1);
    } else {
      *reinterpret_cast<float2*>(Y + (size_t)n2 * COUT + co2 * 2) =
          make_float2(v0, v1);
    }
    __syncthreads();  // protect sAgg before next chunk's phase 1
  }
}

// ================= final FC =================
__global__ __launch_bounds__(256) void fc_kernel(const float* __restrict__ pooled,
                                                 const float* __restrict__ fcw,
                                                 float* __restrict__ out) {
  int b = blockIdx.x >> 1;
  int o = blockIdx.x & 1;
  const float* pb = pooled + b * (G * 32);
  float s = 0.f;
  for (int i = threadIdx.x; i < G * 32; i += 256) {
    float v = pb[i];
    v = isfinite(v) ? v : 0.f;  // untouched cells (0xFF memset -> NaN) -> 0
    s += v * fcw[i * 2 + o];
  }
  __shared__ float red[256];
  red[threadIdx.x] = s;
  __syncthreads();
  for (int st = 128; st > 0; st >>= 1) {
    if (threadIdx.x < st) red[threadIdx.x] += red[threadIdx.x + st];
    __syncthreads();
  }
  if (threadIdx.x == 0) out[b * 2 + o] = red[0];
}

extern "C" void kernel_launch(void* const* d_in, const int* in_sizes, int n_in,
                              void* d_out, int out_size, void* d_ws, size_t ws_size,
                              hipStream_t stream) {
  const float* x     = (const float*)d_in[0];
  const float* pos   = (const float*)d_in[1];
  const float* ea    = (const float*)d_in[2];
  const int*   ei    = (const int*)d_in[3];
  const int*   batch = (const int*)d_in[4];
  const float* fcw   = (const float*)d_in[5];
  const float* w1    = (const float*)d_in[6];
  const float* w2    = (const float*)d_in[7];
  const float* w3    = (const float*)d_in[8];
  const float* w4    = (const float*)d_in[9];
  const float* w5    = (const float*)d_in[10];
  const float* w6    = (const float*)d_in[11];
  const float* w7    = (const float*)d_in[12];
  float* out = (float*)d_out;

  // ---- workspace layout (256B-aligned chunks) ----
  char* ws = (char*)d_ws;
  size_t off = 0;
  auto alloc = [&](size_t bytes) {
    size_t p = off;
    off += (bytes + 255) & ~(size_t)255;
    return ws + p;
  };
  float*  rcnt   = (float*)alloc((size_t)N * 4);
  int*    cnt    = (int*)alloc((size_t)N * 4);
  int*    rowptr = (int*)alloc((size_t)(N + 1) * 4);
  int*    cursor = (int*)alloc((size_t)N * 4);
  int*    bsum   = (int*)alloc(512 * 4);
  int*    boff   = (int*)alloc(512 * 4);
  int2*   sdesc  = (int2*)alloc((size_t)N * 8);
  float4* rec    = (float4*)alloc((size_t)E * 16);
  float*  bufA   = (float*)alloc((size_t)N * 32 * 4);
  float*  bufB   = (float*)alloc((size_t)N * 32 * 4);
  float*  bufC   = (float*)alloc((size_t)N * 32 * 4);
  float*  pooled = (float*)alloc((size_t)B_ * G * 32 * 4);

  // ---- CSR build ----
  hipMemsetAsync(cnt, 0, (size_t)N * 4, stream);
  count_kernel<<<EB, 256, 0, stream>>>(ei, cnt);
  rcnt_kernel<<<NB, 256, 0, stream>>>(cnt, rcnt);
  reduce_cnt<<<NB, 256, 0, stream>>>(cnt, bsum);
  scan_bsum<<<1, 512, 0, stream>>>(bsum, boff);
  write_rowptr<<<NB, 256, 0, stream>>>(cnt, boff, rowptr, cursor, sdesc);
  edge_scatter<<<EB, 256, 0, stream>>>(ei, ea, cursor, rec);

  // ---- pooled init (must precede conv7) ----
  hipMemsetAsync(pooled, 0xFF, (size_t)B_ * G * 32 * 4, stream);

  // ---- conv ladder: persistent 3200-block grid, 32 nodes/block, 8KB LDS ----
  // conv1: 1->8    x -> A     NPB=32 K=1
  node_conv_v11<1, 8, false, false, 1><<<CGRID, 128, 0, stream>>>(
      x, w1, rec, sdesc, rcnt, nullptr, bufA, nullptr, nullptr, nullptr);
  // conv2: 8->16   A -> B     NPB=16 K=2
  node_conv_v11<8, 16, false, false, 2><<<CGRID, 128, 0, stream>>>(
      bufA, w2, rec, sdesc, rcnt, nullptr, bufB, nullptr, nullptr, nullptr);
  // conv3: 16->16  B -> C     NPB=16 K=2
  node_conv_v11<16, 16, false, false, 2><<<CGRID, 128, 0, stream>>>(
      bufB, w3, rec, sdesc, rcnt, nullptr, bufC, nullptr, nullptr, nullptr);
  // conv4: 16->16  C -> A, + residual B
  node_conv_v11<16, 16, true, false, 2><<<CGRID, 128, 0, stream>>>(
      bufC, w4, rec, sdesc, rcnt, bufB, bufA, nullptr, nullptr, nullptr);
  // conv5: 16->32  A -> C     NPB=8 K=4
  node_conv_v11<16, 32, false, false, 4><<<CGRID, 128, 0, stream>>>(
      bufA, w5, rec, sdesc, rcnt, nullptr, bufC, nullptr, nullptr, nullptr);
  // conv6: 32->32  C -> B     NPB=8 K=4
  node_conv_v11<32, 32, false, false, 4><<<CGRID, 128, 0, stream>>>(
      bufC, w6, rec, sdesc, rcnt, nullptr, bufB, nullptr, nullptr, nullptr);
  // conv7: 32->32  B -> (pool), + residual C
  node_conv_v11<32, 32, true, true, 4><<<CGRID, 128, 0, stream>>>(
      bufB, w7, rec, sdesc, rcnt, bufC, nullptr, pos, batch, pooled);

  // ---- FC ----
  fc_kernel<<<B_ * 2, 256, 0, stream>>>(pooled, fcw, out);
}

// Round 7
// 1041.683 us; speedup vs baseline: 2.8573x; 1.1278x over previous
//
#include <hip/hip_runtime.h>
#include <math.h>

// ---- static problem config (matches reference) ----
namespace {
constexpr int N  = 102400;   // nodes
constexpr int E  = 819200;   // edges
constexpr int B_ = 16;       // graphs
constexpr int G  = 72;       // voxel cells per graph (8 x 9)
constexpr int GX = 8;
constexpr int NB = N / 256;  // 400 blocks over nodes
constexpr int EB = E / 256;  // 3200 blocks over edges
}

// ================= CSR build =================

__global__ __launch_bounds__(256) void count_kernel(const int* __restrict__ ei,
                                                    int* __restrict__ cnt) {
  int e = blockIdx.x * 256 + threadIdx.x;
  atomicAdd(&cnt[ei[E + e]], 1);
}

__global__ __launch_bounds__(256) void rcnt_kernel(const int* __restrict__ cnt,
                                                   float* __restrict__ rcnt) {
  int n = blockIdx.x * 256 + threadIdx.x;
  rcnt[n] = 1.0f / (float)max(cnt[n], 1);
}

// per-256-chunk sums of cnt
__global__ __launch_bounds__(256) void reduce_cnt(const int* __restrict__ cnt,
                                                  int* __restrict__ bsum) {
  __shared__ int s[256];
  int i = blockIdx.x * 256 + threadIdx.x;
  s[threadIdx.x] = cnt[i];
  __syncthreads();
  for (int st = 128; st > 0; st >>= 1) {
    if (threadIdx.x < st) s[threadIdx.x] += s[threadIdx.x + st];
    __syncthreads();
  }
  if (threadIdx.x == 0) bsum[blockIdx.x] = s[0];
}

// single-block exclusive scan of the NB block sums
__global__ __launch_bounds__(512) void scan_bsum(const int* __restrict__ bsum,
                                                 int* __restrict__ boff) {
  __shared__ int s[512];
  int i = threadIdx.x;
  int v = (i < NB) ? bsum[i] : 0;
  s[i] = v;
  __syncthreads();
  for (int st = 1; st < 512; st <<= 1) {
    int t = (i >= st) ? s[i - st] : 0;
    __syncthreads();
    s[i] += t;
    __syncthreads();
  }
  if (i < NB) boff[i] = s[i] - v;  // exclusive
}

// rowptr[n] = exclusive scan of cnt; cursor = rowptr; sdesc[n] = (beg, end)
__global__ __launch_bounds__(256) void write_rowptr(const int* __restrict__ cnt,
                                                    const int* __restrict__ boff,
                                                    int* __restrict__ rowptr,
                                                    int* __restrict__ cursor,
                                                    int2* __restrict__ sdesc) {
  __shared__ int s[256];
  int i = blockIdx.x * 256 + threadIdx.x;
  int v = cnt[i];
  s[threadIdx.x] = v;
  __syncthreads();
  for (int st = 1; st < 256; st <<= 1) {
    int t = (threadIdx.x >= st) ? s[threadIdx.x - st] : 0;
    __syncthreads();
    s[threadIdx.x] += t;
    __syncthreads();
  }
  int off = boff[blockIdx.x] + s[threadIdx.x] - v;  // exclusive
  rowptr[i] = off;
  cursor[i] = off;
  sdesc[i] = make_int2(off, off + v);
  if (i == N - 1) rowptr[N] = off + v;
}

// scatter edge records (src + clamped pseudo-coords) into CSR order
__global__ __launch_bounds__(256) void edge_scatter(const int* __restrict__ ei,
                                                    const float* __restrict__ ea,
                                                    int* __restrict__ cursor,
                                                    float4* __restrict__ rec) {
  int e = blockIdx.x * 256 + threadIdx.x;
  int src = ei[e];
  int dst = ei[E + e];
  float u0 = fminf(fmaxf(ea[3 * e + 0], 0.f), 1.f);
  float u1 = fminf(fmaxf(ea[3 * e + 1], 0.f), 1.f);
  float u2 = fminf(fmaxf(ea[3 * e + 2], 0.f), 1.f);
  int slot = atomicAdd(&cursor[dst], 1);
  rec[slot] = make_float4(__int_as_float(src), u0, u1, u2);
}

// ================= pooling helper =================
__device__ __forceinline__ void atomicMaxFloat(float* addr, float val) {
  if (val >= 0.f)
    atomicMax(reinterpret_cast<int*>(addr), __float_as_int(val));
  else
    atomicMin(reinterpret_cast<unsigned int*>(addr), __float_as_uint(val));
}

// ====== v12: v7 block structure + float2 phase-2 (8 KB LDS) ======
// out[n] = (1/deg) * sum_k ( sum_{e->n} b_k(e) * x_src(e) ) @ W[k]
//
// Round-18. A/B across v7..v11 isolated the spill trigger: v7's body
// (no outer chunk loop, hoisted epilogue, 128 threads, bounds(128,6))
// allocates 56 VGPR clean; adding the K-chunk g-loop (v10b/v11, same
// phase-1, same bound) makes the allocator down-allocate to 32/40 VGPR
// and scratch-spill agg[] (250MB-1GB round-trip traffic, scratch-latency
// bound). Fix: DELETE the g-loop (v7 structure: one NPB-node chunk per
// block) and keep only the LDS halving via float2 phase-2 (TPN=COUT/2,
// verified correct in v10b/v11). LDS: conv3/4/6/7 = 8 KB, conv2/5 = 4 KB,
// conv1 = 1.5 KB -> resident cap = wave slots = 16 two-wave blocks/CU
// (32 waves/CU, vs v7's 20-wave LDS cap). Grids = N/NPB; conv3 6400 vs
// 4096 resident = 2 lockstep rounds at ~32 and ~18 waves/CU -> time-avg
// ~25 waves/CU, 2x v7's 12.5.
template <int CIN, int COUT, bool RES, bool POOL>
__global__ __launch_bounds__(128, 6) void node_conv_v12(
    const float* __restrict__ X, const float* __restrict__ W,
    const float4* __restrict__ rec, const int2* __restrict__ sdesc,
    const float* __restrict__ rcnt, const float* __restrict__ res,
    float* __restrict__ Y, const float* __restrict__ pos,
    const int* __restrict__ batch, float* __restrict__ pooled) {
  constexpr int TPN  = COUT / 2;                    // phase-2 threads per node
  constexpr int NPB  = 128 / TPN;                   // nodes per block
  constexpr int ROWF = (CIN >= 8) ? 8 * CIN : 12;   // LDS floats per node row

  __shared__ float sAgg[NPB * ROWF];

  const int tid  = threadIdx.x;
  const int wave = tid >> 6;
  const int lane = tid & 63;

  // XCD swizzle: consecutive node chunks land on one XCD
  const int sb = (blockIdx.x & 7) * (gridDim.x >> 3) + (blockIdx.x >> 3);
  const int nbase = sb * NPB;

  // ---- phase-2 epilogue gathers hoisted to top (overlap phase 1) ----
  const int node_l = tid / TPN;
  const int co2    = tid % TPN;
  const int n2 = nbase + node_l;
  const float rc = rcnt[n2];
  float2 rres = make_float2(0.f, 0.f);
  if constexpr (RES)
    rres = *reinterpret_cast<const float2*>(res + (size_t)n2 * COUT + co2 * 2);
  float p0 = 0.f, p1 = 0.f;
  int bi = 0;
  if constexpr (POOL) {
    p0 = pos[n2 * 3 + 0];
    p1 = pos[n2 * 3 + 1];
    bi = batch[n2];
  }

  // ---------------- phase 1 ----------------
  if constexpr (CIN >= 8) {
    constexpr int QN   = CIN / 4;          // channel quads per row
    constexpr int LPN  = 8 * QN;           // lanes per node
    constexpr int NPW  = 64 / LPN;         // nodes per wave per rep
    constexpr int REPS = NPB / (2 * NPW);  // reps per wave

    const int ci4  = lane % QN;
    const int esub = (lane / QN) & 7;
    const int ns   = lane / LPN;
    const int kstar = ((lane / QN) & 1) * 4 + ((lane / (2 * QN)) & 1) * 2 +
                      ((lane / (4 * QN)) & 1);
    const int slot0 = wave * (REPS * NPW) + ns;  // local slot of rep 0

    auto loadDesc = [&](int rep) -> int2 {
      int r = min(rep, REPS - 1);
      return sdesc[nbase + slot0 + r * NPW];
    };
    auto loadRec = [&](int e) -> float4 { return rec[min(e, E - 1)]; };
    auto loadX = [&](const float4& r) -> float4 {
      int src = __float_as_int(r.x);
      return *(reinterpret_cast<const float4*>(X + (size_t)src * CIN) + ci4);
    };

    // pipeline prologue
    int2 d0 = loadDesc(0);
    int2 d1 = loadDesc(1);
    int2 d2 = loadDesc(2);
    float4 ra0 = loadRec(d0.x + esub), rb0 = loadRec(d0.x + esub + 8);
    float4 ra1 = loadRec(d1.x + esub), rb1 = loadRec(d1.x + esub + 8);
    float4 xa0 = loadX(ra0), xb0 = loadX(rb0);

#pragma unroll 1
    for (int rep = 0; rep < REPS; rep++) {
      // issue next-rep x pair (recs arrived one rep ago)
      float4 xa1 = loadX(ra1), xb1 = loadX(rb1);
      // issue rep+2 rec pair (desc arrived one rep ago)
      float4 ra2 = loadRec(d2.x + esub), rb2 = loadRec(d2.x + esub + 8);
      // issue rep+3 desc
      int2 d3 = loadDesc(rep + 3);

      float agg[32];
#pragma unroll
      for (int i = 0; i < 32; i++) agg[i] = 0.f;

      auto accum = [&](const float4& r, const float4& v, bool valid) {
        float uy = r.y, uz = r.z, uw = r.w;
        float py = 1.f - uy, pz = 1.f - uz, pw = 1.f - uw;
        float g2 = valid ? 1.f : 0.f;
        float t0 = py * pz * g2, t1 = uy * pz * g2;
        float t2 = py * uz * g2, t3 = uy * uz * g2;
        float b[8] = {t0 * pw, t1 * pw, t2 * pw, t3 * pw,
                      t0 * uw, t1 * uw, t2 * uw, t3 * uw};
#pragma unroll
        for (int k = 0; k < 8; k++) {
          agg[k * 4 + 0] = fmaf(b[k], v.x, agg[k * 4 + 0]);
          agg[k * 4 + 1] = fmaf(b[k], v.y, agg[k * 4 + 1]);
          agg[k * 4 + 2] = fmaf(b[k], v.z, agg[k * 4 + 2]);
          agg[k * 4 + 3] = fmaf(b[k], v.w, agg[k * 4 + 3]);
        }
      };

      accum(ra0, xa0, d0.x + esub < d0.y);
      accum(rb0, xb0, d0.x + esub + 8 < d0.y);
      // rare: deg > 16 (P ~ 0.4%), exposed-latency fallback
#pragma unroll 1
      for (int e = d0.x + esub + 16; e < d0.y; e += 8) {
        float4 rr = rec[e];
        float4 xx = loadX(rr);
        accum(rr, xx, true);
      }

      // reduce-and-split over esub bits; payload 32 -> 16 -> 8 -> 4
#pragma unroll
      for (int s = 0; s < 3; s++) {
        const int m = QN << s;
        const int H = 16 >> s;
        bool up = (lane & m) != 0;
#pragma unroll
        for (int i = 0; i < H; i++) {
          float keep = up ? agg[i + H] : agg[i];
          float send = up ? agg[i] : agg[i + H];
          agg[i] = keep + __shfl_xor(send, m, 64);
        }
      }

      const int sl = slot0 + rep * NPW;
      const int idx4 = (kstar * QN + ci4) ^ (sl & 7);  // block swizzle
      *reinterpret_cast<float4*>(&sAgg[sl * ROWF + idx4 * 4]) =
          make_float4(agg[0], agg[1], agg[2], agg[3]);

      // rotate pipeline
      d0 = d1; d1 = d2; d2 = d3;
      ra0 = ra1; rb0 = rb1; ra1 = ra2; rb1 = rb2;
      xa0 = xa1; xb0 = xb1;
    }
  } else {
    // CIN == 1: lane = (node_sub, k); serial edge walk with prefetch
    constexpr int LPN  = 8;
    constexpr int NPW  = 8;
    constexpr int REPS = NPB / (2 * NPW);
    const int ns = lane / LPN;
    const int k  = lane & 7;
    const int slotbase = nbase + wave * (REPS * NPW) + ns;

    int2 seC = sdesc[slotbase];
    int2 seN = (REPS > 1) ? sdesc[slotbase + NPW] : seC;
    float4 rcC = make_float4(0.f, 0.f, 0.f, 0.f);
    bool vC = seC.x < seC.y;
    if (vC) rcC = rec[seC.x];

#pragma unroll 1
    for (int rep = 0; rep < REPS; rep++) {
      bool vN = (rep + 1 < REPS) && (seN.x < seN.y);
      float4 rcN = make_float4(0.f, 0.f, 0.f, 0.f);
      if (vN) rcN = rec[seN.x];
      int2 seNN = (rep + 2 < REPS) ? sdesc[slotbase + (rep + 2) * NPW] : seN;

      float a0 = 0.f;
      if (vC) {
        float4 r = rcC;
        int e = seC.x + 1;
        while (true) {
          bool more = e < seC.y;
          float4 rn = r;
          if (more) rn = rec[e];
          int src = __float_as_int(r.x);
          float f0 = (k & 1) ? r.y : 1.f - r.y;
          float f1 = (k & 2) ? r.z : 1.f - r.z;
          float f2 = (k & 4) ? r.w : 1.f - r.w;
          a0 = fmaf(f0 * f1 * f2, X[src], a0);
          if (!more) break;
          r = rn;
          e++;
        }
      }

      const int sl = wave * (REPS * NPW) + rep * NPW + ns;
      sAgg[sl * ROWF + k] = a0;

      seC = seN;
      seN = seNN;
      vC = vN;
      rcC = rcN;
    }
  }
  __syncthreads();

  // ---------------- phase 2 (float2 per thread) ----------------
  float2 acc = make_float2(0.f, 0.f);
  const float2* W2 = reinterpret_cast<const float2*>(W);
  const float* arow = &sAgg[node_l * ROWF];

  if constexpr (CIN == 1) {
#pragma unroll
    for (int kk = 0; kk < 8; kk++) {
      float a = arow[kk];
      float2 w = W2[kk * TPN + co2];
      acc.x = fmaf(a, w.x, acc.x);
      acc.y = fmaf(a, w.y, acc.y);
    }
  } else {
    constexpr int Q = CIN / 4;
    const int swz = node_l & 7;
#pragma unroll 2
    for (int kk = 0; kk < 8; kk++) {
#pragma unroll
      for (int c = 0; c < Q; c++) {
        float4 a4 = *reinterpret_cast<const float4*>(
            &arow[((kk * Q + c) ^ swz) * 4]);
        float2 w0 = W2[(kk * CIN + 4 * c + 0) * TPN + co2];
        float2 w1 = W2[(kk * CIN + 4 * c + 1) * TPN + co2];
        float2 w2 = W2[(kk * CIN + 4 * c + 2) * TPN + co2];
        float2 w3 = W2[(kk * CIN + 4 * c + 3) * TPN + co2];
        acc.x = fmaf(a4.x, w0.x, acc.x);
        acc.y = fmaf(a4.x, w0.y, acc.y);
        acc.x = fmaf(a4.y, w1.x, acc.x);
        acc.y = fmaf(a4.y, w1.y, acc.y);
        acc.x = fmaf(a4.z, w2.x, acc.x);
        acc.y = fmaf(a4.z, w2.y, acc.y);
        acc.x = fmaf(a4.w, w3.x, acc.x);
        acc.y = fmaf(a4.w, w3.y, acc.y);
      }
    }
  }

  float v0 = acc.x * rc;
  float v1 = acc.y * rc;
  v0 = v0 > 0.f ? v0 : expm1f(v0);
  v1 = v1 > 0.f ? v1 : expm1f(v1);
  if constexpr (RES) {
    v0 += rres.x;
    v1 += rres.y;
  }

  if constexpr (POOL) {
    int cx = (int)floorf(p0 / 16.0f);
    int cy = (int)floorf(p1 / 12.0f);
    int cl = bi * G + cy * GX + cx;
    atomicMaxFloat(&pooled[cl * 32 + co2 * 2 + 0], v0);
    atomicMaxFloat(&pooled[cl * 32 + co2 * 2 + 1], v1);
  } else {
    *reinterpret_cast<float2*>(Y + (size_t)n2 * COUT + co2 * 2) =
        make_float2(v0, v1);
  }
}

// ================= final FC =================
__global__ __launch_bounds__(256) void fc_kernel(const float* __restrict__ pooled,
                                                 const float* __restrict__ fcw,
                                                 float* __restrict__ out) {
  int b = blockIdx.x >> 1;
  int o = blockIdx.x & 1;
  const float* pb = pooled + b * (G * 32);
  float s = 0.f;
  for (int i = threadIdx.x; i < G * 32; i += 256) {
    float v = pb[i];
    v = isfinite(v) ? v : 0.f;  // untouched cells (0xFF memset -> NaN) -> 0
    s += v * fcw[i * 2 + o];
  }
  __shared__ float red[256];
  red[threadIdx.x] = s;
  __syncthreads();
  for (int st = 128; st > 0; st >>= 1) {
    if (threadIdx.x < st) red[threadIdx.x] += red[threadIdx.x + st];
    __syncthreads();
  }
  if (threadIdx.x == 0) out[b * 2 + o] = red[0];
}

extern "C" void kernel_launch(void* const* d_in, const int* in_sizes, int n_in,
                              void* d_out, int out_size, void* d_ws, size_t ws_size,
                              hipStream_t stream) {
  const float* x     = (const float*)d_in[0];
  const float* pos   = (const float*)d_in[1];
  const float* ea    = (const float*)d_in[2];
  const int*   ei    = (const int*)d_in[3];
  const int*   batch = (const int*)d_in[4];
  const float* fcw   = (const float*)d_in[5];
  const float* w1    = (const float*)d_in[6];
  const float* w2    = (const float*)d_in[7];
  const float* w3    = (const float*)d_in[8];
  const float* w4    = (const float*)d_in[9];
  const float* w5    = (const float*)d_in[10];
  const float* w6    = (const float*)d_in[11];
  const float* w7    = (const float*)d_in[12];
  float* out = (float*)d_out;

  // ---- workspace layout (256B-aligned chunks) ----
  char* ws = (char*)d_ws;
  size_t off = 0;
  auto alloc = [&](size_t bytes) {
    size_t p = off;
    off += (bytes + 255) & ~(size_t)255;
    return ws + p;
  };
  float*  rcnt   = (float*)alloc((size_t)N * 4);
  int*    cnt    = (int*)alloc((size_t)N * 4);
  int*    rowptr = (int*)alloc((size_t)(N + 1) * 4);
  int*    cursor = (int*)alloc((size_t)N * 4);
  int*    bsum   = (int*)alloc(512 * 4);
  int*    boff   = (int*)alloc(512 * 4);
  int2*   sdesc  = (int2*)alloc((size_t)N * 8);
  float4* rec    = (float4*)alloc((size_t)E * 16);
  float*  bufA   = (float*)alloc((size_t)N * 32 * 4);
  float*  bufB   = (float*)alloc((size_t)N * 32 * 4);
  float*  bufC   = (float*)alloc((size_t)N * 32 * 4);
  float*  pooled = (float*)alloc((size_t)B_ * G * 32 * 4);

  // ---- CSR build ----
  hipMemsetAsync(cnt, 0, (size_t)N * 4, stream);
  count_kernel<<<EB, 256, 0, stream>>>(ei, cnt);
  rcnt_kernel<<<NB, 256, 0, stream>>>(cnt, rcnt);
  reduce_cnt<<<NB, 256, 0, stream>>>(cnt, bsum);
  scan_bsum<<<1, 512, 0, stream>>>(bsum, boff);
  write_rowptr<<<NB, 256, 0, stream>>>(cnt, boff, rowptr, cursor, sdesc);
  edge_scatter<<<EB, 256, 0, stream>>>(ei, ea, cursor, rec);

  // ---- pooled init (must precede conv7) ----
  hipMemsetAsync(pooled, 0xFF, (size_t)B_ * G * 32 * 4, stream);

  // ---- conv ladder: one chunk per block (v7 structure), float2 phase-2 ----
  // conv1: 1->8    x -> A     NPB=32, grid 3200, LDS 1.5 KB
  node_conv_v12<1, 8, false, false><<<N / 32, 128, 0, stream>>>(
      x, w1, rec, sdesc, rcnt, nullptr, bufA, nullptr, nullptr, nullptr);
  // conv2: 8->16   A -> B     NPB=16, grid 6400, LDS 4 KB
  node_conv_v12<8, 16, false, false><<<N / 16, 128, 0, stream>>>(
      bufA, w2, rec, sdesc, rcnt, nullptr, bufB, nullptr, nullptr, nullptr);
  // conv3: 16->16  B -> C     NPB=16, grid 6400, LDS 8 KB
  node_conv_v12<16, 16, false, false><<<N / 16, 128, 0, stream>>>(
      bufB, w3, rec, sdesc, rcnt, nullptr, bufC, nullptr, nullptr, nullptr);
  // conv4: 16->16  C -> A, + residual B
  node_conv_v12<16, 16, true, false><<<N / 16, 128, 0, stream>>>(
      bufC, w4, rec, sdesc, rcnt, bufB, bufA, nullptr, nullptr, nullptr);
  // conv5: 16->32  A -> C     NPB=8, grid 12800, LDS 4 KB
  node_conv_v12<16, 32, false, false><<<N / 8, 128, 0, stream>>>(
      bufA, w5, rec, sdesc, rcnt, nullptr, bufC, nullptr, nullptr, nullptr);
  // conv6: 32->32  C -> B     NPB=8, grid 12800, LDS 8 KB
  node_conv_v12<32, 32, false, false><<<N / 8, 128, 0, stream>>>(
      bufC, w6, rec, sdesc, rcnt, nullptr, bufB, nullptr, nullptr, nullptr);
  // conv7: 32->32  B -> (pool), + residual C
  node_conv_v12<32, 32, true, true><<<N / 8, 128, 0, stream>>>(
      bufB, w7, rec, sdesc, rcnt, bufC, nullptr, pos, batch, pooled);

  // ---- FC ----
  fc_kernel<<<B_ * 2, 256, 0, stream>>>(pooled, fcw, out);
}

// Round 8
// 695.931 us; speedup vs baseline: 4.2769x; 1.4968x over previous
//
#include <hip/hip_runtime.h>
#include <math.h>

// ---- static problem config (matches reference) ----
namespace {
constexpr int N  = 102400;   // nodes
constexpr int E  = 819200;   // edges
constexpr int B_ = 16;       // graphs
constexpr int G  = 72;       // voxel cells per graph (8 x 9)
constexpr int GX = 8;
constexpr int NB = N / 256;  // 400 blocks over nodes
constexpr int EB = E / 256;  // 3200 blocks over edges
}

// ================= CSR build =================

__global__ __launch_bounds__(256) void count_kernel(const int* __restrict__ ei,
                                                    int* __restrict__ cnt) {
  int e = blockIdx.x * 256 + threadIdx.x;
  atomicAdd(&cnt[ei[E + e]], 1);
}

__global__ __launch_bounds__(256) void rcnt_kernel(const int* __restrict__ cnt,
                                                   float* __restrict__ rcnt) {
  int n = blockIdx.x * 256 + threadIdx.x;
  rcnt[n] = 1.0f / (float)max(cnt[n], 1);
}

// per-256-chunk sums of cnt
__global__ __launch_bounds__(256) void reduce_cnt(const int* __restrict__ cnt,
                                                  int* __restrict__ bsum) {
  __shared__ int s[256];
  int i = blockIdx.x * 256 + threadIdx.x;
  s[threadIdx.x] = cnt[i];
  __syncthreads();
  for (int st = 128; st > 0; st >>= 1) {
    if (threadIdx.x < st) s[threadIdx.x] += s[threadIdx.x + st];
    __syncthreads();
  }
  if (threadIdx.x == 0) bsum[blockIdx.x] = s[0];
}

// single-block exclusive scan of the NB block sums
__global__ __launch_bounds__(512) void scan_bsum(const int* __restrict__ bsum,
                                                 int* __restrict__ boff) {
  __shared__ int s[512];
  int i = threadIdx.x;
  int v = (i < NB) ? bsum[i] : 0;
  s[i] = v;
  __syncthreads();
  for (int st = 1; st < 512; st <<= 1) {
    int t = (i >= st) ? s[i - st] : 0;
    __syncthreads();
    s[i] += t;
    __syncthreads();
  }
  if (i < NB) boff[i] = s[i] - v;  // exclusive
}

// rowptr[n] = exclusive scan of cnt; cursor = rowptr; sdesc[n] = (beg, end)
__global__ __launch_bounds__(256) void write_rowptr(const int* __restrict__ cnt,
                                                    const int* __restrict__ boff,
                                                    int* __restrict__ rowptr,
                                                    int* __restrict__ cursor,
                                                    int2* __restrict__ sdesc) {
  __shared__ int s[256];
  int i = blockIdx.x * 256 + threadIdx.x;
  int v = cnt[i];
  s[threadIdx.x] = v;
  __syncthreads();
  for (int st = 1; st < 256; st <<= 1) {
    int t = (threadIdx.x >= st) ? s[threadIdx.x - st] : 0;
    __syncthreads();
    s[threadIdx.x] += t;
    __syncthreads();
  }
  int off = boff[blockIdx.x] + s[threadIdx.x] - v;  // exclusive
  rowptr[i] = off;
  cursor[i] = off;
  sdesc[i] = make_int2(off, off + v);
  if (i == N - 1) rowptr[N] = off + v;
}

// scatter edge records (src + clamped pseudo-coords) into CSR order
__global__ __launch_bounds__(256) void edge_scatter(const int* __restrict__ ei,
                                                    const float* __restrict__ ea,
                                                    int* __restrict__ cursor,
                                                    float4* __restrict__ rec) {
  int e = blockIdx.x * 256 + threadIdx.x;
  int src = ei[e];
  int dst = ei[E + e];
  float u0 = fminf(fmaxf(ea[3 * e + 0], 0.f), 1.f);
  float u1 = fminf(fmaxf(ea[3 * e + 1], 0.f), 1.f);
  float u2 = fminf(fmaxf(ea[3 * e + 2], 0.f), 1.f);
  int slot = atomicAdd(&cursor[dst], 1);
  rec[slot] = make_float4(__int_as_float(src), u0, u1, u2);
}

// ================= pooling helper =================
__device__ __forceinline__ void atomicMaxFloat(float* addr, float val) {
  if (val >= 0.f)
    atomicMax(reinterpret_cast<int*>(addr), __float_as_int(val));
  else
    atomicMin(reinterpret_cast<unsigned int*>(addr), __float_as_uint(val));
}

// ====== v13: v7 float4 body + K-chunk loop (full residency) ======
// out[n] = (1/deg) * sum_k ( sum_{e->n} b_k(e) * x_src(e) ) @ W[k]
//
// Round-19. Spill trigger finally de-confounded by elimination:
//   float4 phase-2, no g-loop (v6,v7)  -> clean (56 VGPR, ideal traffic)
//   float2 phase-2, no g-loop (v12)    -> SPILL (40 VGPR, +300MB scratch)
//   float2 phase-2, g-loop (v10b,v11)  -> SPILL
// => float2 phase-2 is the trigger; the g-loop was never tested alone.
// v13 = v7's EXACT body (phase-1, float4 phase-2, epilogue; clean twice)
// wrapped in a K-chunk loop so every conv's grid fits residency:
//   conv3/4 (16KB LDS, cap 10 blk/CU=2560): K=2 -> grid 1600, all resident
//   conv6/7 (16KB): K=4 -> grid 1600;  conv5 (8KB): K=2 -> grid 3200
//   conv2 (8KB): K=1 grid 3200;        conv1 (3KB): K=1 grid 1600
// Single pass, zero round-quantization -> sustained ~20 waves/CU (62%)
// vs v7's 12.5 avg. REPS stays 8 for all 16/32-ch convs (as v7).
template <int CIN, int COUT, bool RES, bool POOL, int K>
__global__ __launch_bounds__(128, 6) void node_conv_v13(
    const float* __restrict__ X, const float* __restrict__ W,
    const float4* __restrict__ rec, const int2* __restrict__ sdesc,
    const float* __restrict__ rcnt, const float* __restrict__ res,
    float* __restrict__ Y, const float* __restrict__ pos,
    const int* __restrict__ batch, float* __restrict__ pooled) {
  constexpr int TPN  = COUT / 4;                    // phase-2 threads per node
  constexpr int NPB  = 128 / TPN;                   // nodes per block-chunk
  constexpr int ROWF = (CIN >= 8) ? 8 * CIN : 12;   // LDS floats per node row

  __shared__ float sAgg[NPB * ROWF];

  const int tid  = threadIdx.x;
  const int wave = tid >> 6;
  const int lane = tid & 63;

  // XCD swizzle: consecutive node ranges land on one XCD
  const int sb = (blockIdx.x & 7) * (gridDim.x >> 3) + (blockIdx.x >> 3);
  const int bbase = sb * (K * NPB);

  const int node_l = tid / TPN;
  const int co4    = tid % TPN;

#pragma unroll 1
  for (int g = 0; g < K; g++) {
    const int nbase = bbase + g * NPB;

    // ---- phase-2 epilogue gathers hoisted to chunk top (overlap phase 1) ----
    const int n2 = nbase + node_l;
    const float rc = rcnt[n2];
    float4 rres = make_float4(0.f, 0.f, 0.f, 0.f);
    if constexpr (RES)
      rres = *reinterpret_cast<const float4*>(res + (size_t)n2 * COUT + co4 * 4);
    float p0 = 0.f, p1 = 0.f;
    int bi = 0;
    if constexpr (POOL) {
      p0 = pos[n2 * 3 + 0];
      p1 = pos[n2 * 3 + 1];
      bi = batch[n2];
    }

    // ---------------- phase 1 ----------------
    if constexpr (CIN >= 8) {
      constexpr int QN   = CIN / 4;          // channel quads per row
      constexpr int LPN  = 8 * QN;           // lanes per node
      constexpr int NPW  = 64 / LPN;         // nodes per wave per rep
      constexpr int REPS = NPB / (2 * NPW);  // reps per wave

      const int ci4  = lane % QN;
      const int esub = (lane / QN) & 7;
      const int ns   = lane / LPN;
      const int kstar = ((lane / QN) & 1) * 4 + ((lane / (2 * QN)) & 1) * 2 +
                        ((lane / (4 * QN)) & 1);
      const int slot0 = wave * (REPS * NPW) + ns;  // local slot of rep 0

      auto loadDesc = [&](int rep) -> int2 {
        int r = min(rep, REPS - 1);
        return sdesc[nbase + slot0 + r * NPW];
      };
      auto loadRec = [&](int e) -> float4 { return rec[min(e, E - 1)]; };
      auto loadX = [&](const float4& r) -> float4 {
        int src = __float_as_int(r.x);
        return *(reinterpret_cast<const float4*>(X + (size_t)src * CIN) + ci4);
      };

      // pipeline prologue
      int2 d0 = loadDesc(0);
      int2 d1 = loadDesc(1);
      int2 d2 = loadDesc(2);
      float4 ra0 = loadRec(d0.x + esub), rb0 = loadRec(d0.x + esub + 8);
      float4 ra1 = loadRec(d1.x + esub), rb1 = loadRec(d1.x + esub + 8);
      float4 xa0 = loadX(ra0), xb0 = loadX(rb0);

#pragma unroll 1
      for (int rep = 0; rep < REPS; rep++) {
        // issue next-rep x pair (recs arrived one rep ago)
        float4 xa1 = loadX(ra1), xb1 = loadX(rb1);
        // issue rep+2 rec pair (desc arrived one rep ago)
        float4 ra2 = loadRec(d2.x + esub), rb2 = loadRec(d2.x + esub + 8);
        // issue rep+3 desc
        int2 d3 = loadDesc(rep + 3);

        float agg[32];
#pragma unroll
        for (int i = 0; i < 32; i++) agg[i] = 0.f;

        auto accum = [&](const float4& r, const float4& v, bool valid) {
          float uy = r.y, uz = r.z, uw = r.w;
          float py = 1.f - uy, pz = 1.f - uz, pw = 1.f - uw;
          float g2 = valid ? 1.f : 0.f;
          float t0 = py * pz * g2, t1 = uy * pz * g2;
          float t2 = py * uz * g2, t3 = uy * uz * g2;
          float b[8] = {t0 * pw, t1 * pw, t2 * pw, t3 * pw,
                        t0 * uw, t1 * uw, t2 * uw, t3 * uw};
#pragma unroll
          for (int k = 0; k < 8; k++) {
            agg[k * 4 + 0] = fmaf(b[k], v.x, agg[k * 4 + 0]);
            agg[k * 4 + 1] = fmaf(b[k], v.y, agg[k * 4 + 1]);
            agg[k * 4 + 2] = fmaf(b[k], v.z, agg[k * 4 + 2]);
            agg[k * 4 + 3] = fmaf(b[k], v.w, agg[k * 4 + 3]);
          }
        };

        accum(ra0, xa0, d0.x + esub < d0.y);
        accum(rb0, xb0, d0.x + esub + 8 < d0.y);
        // rare: deg > 16 (P ~ 0.4%), exposed-latency fallback
#pragma unroll 1
        for (int e = d0.x + esub + 16; e < d0.y; e += 8) {
          float4 rr = rec[e];
          float4 xx = loadX(rr);
          accum(rr, xx, true);
        }

        // reduce-and-split over esub bits; payload 32 -> 16 -> 8 -> 4
#pragma unroll
        for (int s = 0; s < 3; s++) {
          const int m = QN << s;
          const int H = 16 >> s;
          bool up = (lane & m) != 0;
#pragma unroll
          for (int i = 0; i < H; i++) {
            float keep = up ? agg[i + H] : agg[i];
            float send = up ? agg[i] : agg[i + H];
            agg[i] = keep + __shfl_xor(send, m, 64);
          }
        }

        const int sl = slot0 + rep * NPW;
        const int idx4 = (kstar * QN + ci4) ^ (sl & 7);  // block swizzle
        *reinterpret_cast<float4*>(&sAgg[sl * ROWF + idx4 * 4]) =
            make_float4(agg[0], agg[1], agg[2], agg[3]);

        // rotate pipeline
        d0 = d1; d1 = d2; d2 = d3;
        ra0 = ra1; rb0 = rb1; ra1 = ra2; rb1 = rb2;
        xa0 = xa1; xb0 = xb1;
      }
    } else {
      // CIN == 1: lane = (node_sub, k); serial edge walk with prefetch
      constexpr int LPN  = 8;
      constexpr int NPW  = 8;
      constexpr int REPS = NPB / (2 * NPW);
      const int ns = lane / LPN;
      const int k  = lane & 7;
      const int slotbase = nbase + wave * (REPS * NPW) + ns;

      int2 seC = sdesc[slotbase];
      int2 seN = (REPS > 1) ? sdesc[slotbase + NPW] : seC;
      float4 rcC = make_float4(0.f, 0.f, 0.f, 0.f);
      bool vC = seC.x < seC.y;
      if (vC) rcC = rec[seC.x];

#pragma unroll 1
      for (int rep = 0; rep < REPS; rep++) {
        bool vN = (rep + 1 < REPS) && (seN.x < seN.y);
        float4 rcN = make_float4(0.f, 0.f, 0.f, 0.f);
        if (vN) rcN = rec[seN.x];
        int2 seNN = (rep + 2 < REPS) ? sdesc[slotbase + (rep + 2) * NPW] : seN;

        float a0 = 0.f;
        if (vC) {
          float4 r = rcC;
          int e = seC.x + 1;
          while (true) {
            bool more = e < seC.y;
            float4 rn = r;
            if (more) rn = rec[e];
            int src = __float_as_int(r.x);
            float f0 = (k & 1) ? r.y : 1.f - r.y;
            float f1 = (k & 2) ? r.z : 1.f - r.z;
            float f2 = (k & 4) ? r.w : 1.f - r.w;
            a0 = fmaf(f0 * f1 * f2, X[src], a0);
            if (!more) break;
            r = rn;
            e++;
          }
        }

        const int sl = wave * (REPS * NPW) + rep * NPW + ns;
        sAgg[sl * ROWF + k] = a0;

        seC = seN;
        seN = seNN;
        vC = vN;
        rcC = rcN;
      }
    }
    __syncthreads();

    // ---------------- phase 2 (float4 per thread — v7-proven) ----------------
    float4 acc = make_float4(0.f, 0.f, 0.f, 0.f);
    const float4* W4 = reinterpret_cast<const float4*>(W);
    const float* arow = &sAgg[node_l * ROWF];

    if constexpr (CIN == 1) {
#pragma unroll
      for (int kk = 0; kk < 8; kk++) {
        float a = arow[kk];
        float4 w = W4[kk * TPN + co4];
        acc.x = fmaf(a, w.x, acc.x);
        acc.y = fmaf(a, w.y, acc.y);
        acc.z = fmaf(a, w.z, acc.z);
        acc.w = fmaf(a, w.w, acc.w);
      }
    } else {
      constexpr int Q = CIN / 4;
      const int swz = node_l & 7;
#pragma unroll 2
      for (int kk = 0; kk < 8; kk++) {
#pragma unroll
        for (int c = 0; c < Q; c++) {
          float4 a4 = *reinterpret_cast<const float4*>(
              &arow[((kk * Q + c) ^ swz) * 4]);
          float4 w0 = W4[(kk * CIN + 4 * c + 0) * TPN + co4];
          float4 w1 = W4[(kk * CIN + 4 * c + 1) * TPN + co4];
          float4 w2 = W4[(kk * CIN + 4 * c + 2) * TPN + co4];
          float4 w3 = W4[(kk * CIN + 4 * c + 3) * TPN + co4];
          acc.x = fmaf(a4.x, w0.x, acc.x);
          acc.y = fmaf(a4.x, w0.y, acc.y);
          acc.z = fmaf(a4.x, w0.z, acc.z);
          acc.w = fmaf(a4.x, w0.w, acc.w);
          acc.x = fmaf(a4.y, w1.x, acc.x);
          acc.y = fmaf(a4.y, w1.y, acc.y);
          acc.z = fmaf(a4.y, w1.z, acc.z);
          acc.w = fmaf(a4.y, w1.w, acc.w);
          acc.x = fmaf(a4.z, w2.x, acc.x);
          acc.y = fmaf(a4.z, w2.y, acc.y);
          acc.z = fmaf(a4.z, w2.z, acc.z);
          acc.w = fmaf(a4.z, w2.w, acc.w);
          acc.x = fmaf(a4.w, w3.x, acc.x);
          acc.y = fmaf(a4.w, w3.y, acc.y);
          acc.z = fmaf(a4.w, w3.z, acc.z);
          acc.w = fmaf(a4.w, w3.w, acc.w);
        }
      }
    }

    float v[4] = {acc.x, acc.y, acc.z, acc.w};
#pragma unroll
    for (int i = 0; i < 4; i++) {
      float w = v[i] * rc;
      v[i] = w > 0.f ? w : expm1f(w);
    }
    if constexpr (RES) {
      v[0] += rres.x;
      v[1] += rres.y;
      v[2] += rres.z;
      v[3] += rres.w;
    }

    if constexpr (POOL) {
      int cx = (int)floorf(p0 / 16.0f);
      int cy = (int)floorf(p1 / 12.0f);
      int cl = bi * G + cy * GX + cx;
      float* pr = pooled + cl * 32 + co4 * 4;
#pragma unroll
      for (int i = 0; i < 4; i++) atomicMaxFloat(&pr[i], v[i]);
    } else {
      *reinterpret_cast<float4*>(Y + (size_t)n2 * COUT + co4 * 4) =
          make_float4(v[0], v[1], v[2], v[3]);
    }
    __syncthreads();  // protect sAgg before next chunk's phase 1
  }
}

// ================= final FC =================
__global__ __launch_bounds__(256) void fc_kernel(const float* __restrict__ pooled,
                                                 const float* __restrict__ fcw,
                                                 float* __restrict__ out) {
  int b = blockIdx.x >> 1;
  int o = blockIdx.x & 1;
  const float* pb = pooled + b * (G * 32);
  float s = 0.f;
  for (int i = threadIdx.x; i < G * 32; i += 256) {
    float v = pb[i];
    v = isfinite(v) ? v : 0.f;  // untouched cells (0xFF memset -> NaN) -> 0
    s += v * fcw[i * 2 + o];
  }
  __shared__ float red[256];
  red[threadIdx.x] = s;
  __syncthreads();
  for (int st = 128; st > 0; st >>= 1) {
    if (threadIdx.x < st) red[threadIdx.x] += red[threadIdx.x + st];
    __syncthreads();
  }
  if (threadIdx.x == 0) out[b * 2 + o] = red[0];
}

extern "C" void kernel_launch(void* const* d_in, const int* in_sizes, int n_in,
                              void* d_out, int out_size, void* d_ws, size_t ws_size,
                              hipStream_t stream) {
  const float* x     = (const float*)d_in[0];
  const float* pos   = (const float*)d_in[1];
  const float* ea    = (const float*)d_in[2];
  const int*   ei    = (const int*)d_in[3];
  const int*   batch = (const int*)d_in[4];
  const float* fcw   = (const float*)d_in[5];
  const float* w1    = (const float*)d_in[6];
  const float* w2    = (const float*)d_in[7];
  const float* w3    = (const float*)d_in[8];
  const float* w4    = (const float*)d_in[9];
  const float* w5    = (const float*)d_in[10];
  const float* w6    = (const float*)d_in[11];
  const float* w7    = (const float*)d_in[12];
  float* out = (float*)d_out;

  // ---- workspace layout (256B-aligned chunks) ----
  char* ws = (char*)d_ws;
  size_t off = 0;
  auto alloc = [&](size_t bytes) {
    size_t p = off;
    off += (bytes + 255) & ~(size_t)255;
    return ws + p;
  };
  float*  rcnt   = (float*)alloc((size_t)N * 4);
  int*    cnt    = (int*)alloc((size_t)N * 4);
  int*    rowptr = (int*)alloc((size_t)(N + 1) * 4);
  int*    cursor = (int*)alloc((size_t)N * 4);
  int*    bsum   = (int*)alloc(512 * 4);
  int*    boff   = (int*)alloc(512 * 4);
  int2*   sdesc  = (int2*)alloc((size_t)N * 8);
  float4* rec    = (float4*)alloc((size_t)E * 16);
  float*  bufA   = (float*)alloc((size_t)N * 32 * 4);
  float*  bufB   = (float*)alloc((size_t)N * 32 * 4);
  float*  bufC   = (float*)alloc((size_t)N * 32 * 4);
  float*  pooled = (float*)alloc((size_t)B_ * G * 32 * 4);

  // ---- CSR build ----
  hipMemsetAsync(cnt, 0, (size_t)N * 4, stream);
  count_kernel<<<EB, 256, 0, stream>>>(ei, cnt);
  rcnt_kernel<<<NB, 256, 0, stream>>>(cnt, rcnt);
  reduce_cnt<<<NB, 256, 0, stream>>>(cnt, bsum);
  scan_bsum<<<1, 512, 0, stream>>>(bsum, boff);
  write_rowptr<<<NB, 256, 0, stream>>>(cnt, boff, rowptr, cursor, sdesc);
  edge_scatter<<<EB, 256, 0, stream>>>(ei, ea, cursor, rec);

  // ---- pooled init (must precede conv7) ----
  hipMemsetAsync(pooled, 0xFF, (size_t)B_ * G * 32 * 4, stream);

  // ---- conv ladder: v7 body + K-chunk loop, every grid fully resident ----
  // conv1: 1->8    x -> A     NPB=64 K=1, grid 1600, LDS 3 KB
  node_conv_v13<1, 8, false, false, 1><<<N / 64, 128, 0, stream>>>(
      x, w1, rec, sdesc, rcnt, nullptr, bufA, nullptr, nullptr, nullptr);
  // conv2: 8->16   A -> B     NPB=32 K=1, grid 3200, LDS 8 KB
  node_conv_v13<8, 16, false, false, 1><<<N / 32, 128, 0, stream>>>(
      bufA, w2, rec, sdesc, rcnt, nullptr, bufB, nullptr, nullptr, nullptr);
  // conv3: 16->16  B -> C     NPB=32 K=2, grid 1600, LDS 16 KB (cap 10/CU)
  node_conv_v13<16, 16, false, false, 2><<<N / 64, 128, 0, stream>>>(
      bufB, w3, rec, sdesc, rcnt, nullptr, bufC, nullptr, nullptr, nullptr);
  // conv4: 16->16  C -> A, + residual B
  node_conv_v13<16, 16, true, false, 2><<<N / 64, 128, 0, stream>>>(
      bufC, w4, rec, sdesc, rcnt, bufB, bufA, nullptr, nullptr, nullptr);
  // conv5: 16->32  A -> C     NPB=16 K=2, grid 3200, LDS 8 KB
  node_conv_v13<16, 32, false, false, 2><<<N / 32, 128, 0, stream>>>(
      bufA, w5, rec, sdesc, rcnt, nullptr, bufC, nullptr, nullptr, nullptr);
  // conv6: 32->32  C -> B     NPB=16 K=4, grid 1600, LDS 16 KB
  node_conv_v13<32, 32, false, false, 4><<<N / 64, 128, 0, stream>>>(
      bufC, w6, rec, sdesc, rcnt, nullptr, bufB, nullptr, nullptr, nullptr);
  // conv7: 32->32  B -> (pool), + residual C
  node_conv_v13<32, 32, true, true, 4><<<N / 64, 128, 0, stream>>>(
      bufB, w7, rec, sdesc, rcnt, bufC, nullptr, pos, batch, pooled);

  // ---- FC ----
  fc_kernel<<<B_ * 2, 256, 0, stream>>>(pooled, fcw, out);
}